// Round 1
// baseline (394.805 us; speedup 1.0000x reference)
//
#include <hip/hip_runtime.h>
#include <hip/hip_bf16.h>

// TransformerBlock: N=4, T=2048, D=1024 (single-head attn, d_head=1024) + MLP(3) + 2 LN.
// All GEMMs in bf16 MFMA (16x16x32), NT form: C[m][n] = sum_k A[m][k]*Bt[n][k].

typedef __attribute__((ext_vector_type(8))) short short8;
typedef __attribute__((ext_vector_type(4))) short short4v;
typedef __attribute__((ext_vector_type(4))) float float4v;

#define DEVI static __device__ __forceinline__

DEVI float bf2f(short s) {
  union { unsigned u; float f; } c;
  c.u = ((unsigned)(unsigned short)s) << 16;
  return c.f;
}
DEVI short f2bf(float f) {
  union { __hip_bfloat16 h; short s; } c;
  c.h = __float2bfloat16(f);
  return c.s;
}
DEVI void gload_lds16(const void* g, void* l) {
  __builtin_amdgcn_global_load_lds(
      (const __attribute__((address_space(1))) void*)g,
      (__attribute__((address_space(3))) void*)l, 16, 0, 0);
}

// ---------------- GEMM (m97-style): 128x128 tile, BK=32, 4 waves ----------------
// flags: 1=bias, 2=relu, 4=fp32 output (else bf16)
__global__ __launch_bounds__(256) void gemm_nt(
    const short* __restrict__ A, const short* __restrict__ B,
    const float* __restrict__ bias, float alpha, void* __restrict__ Cout,
    int K, int lda, int ldb, int ldc,
    long sA, long sB, long sC, int flags)
{
  __shared__ __attribute__((aligned(16))) short lds[8192];  // A tile 128x32 | B tile 128x32
  short* ldsA = lds;
  short* ldsB = lds + 4096;

  const int tid  = threadIdx.x;
  const int lane = tid & 63;
  const int wid  = tid >> 6;
  const int wr = wid >> 1, wc = wid & 1;   // wave grid 2x2, each wave owns 64x64
  const int lr = lane & 15;                // fragment row (A) / col (B)
  const int kq = lane >> 4;                // k-chunk selector (x8)

  const long m0 = (long)blockIdx.x * 128;
  const long n0 = (long)blockIdx.y * 128;
  const short* Ab = A + (long)blockIdx.z * sA;
  const short* Bb = B + (long)blockIdx.z * sB;

  float4v acc[4][4];
#pragma unroll
  for (int m = 0; m < 4; ++m)
#pragma unroll
    for (int n = 0; n < 4; ++n)
#pragma unroll
      for (int i = 0; i < 4; ++i) acc[m][n][i] = 0.f;

  // staging: tile = 4096 bf16; 256 thr * 8 bf16(16B) = 2048 per round -> 2 rounds
  const int e1 = tid * 8;
  const int e2 = e1 + 2048;
  const int row1 = e1 >> 5, col1 = e1 & 31;
  const int row2 = e2 >> 5, col2 = e2 & 31;
  const short* gA1 = Ab + (m0 + row1) * (long)lda + col1;
  const short* gA2 = Ab + (m0 + row2) * (long)lda + col2;
  const short* gB1 = Bb + (n0 + row1) * (long)ldb + col1;
  const short* gB2 = Bb + (n0 + row2) * (long)ldb + col2;

  for (int k0 = 0; k0 < K; k0 += 32) {
    gload_lds16(gA1 + k0, &ldsA[e1]);
    gload_lds16(gA2 + k0, &ldsA[e2]);
    gload_lds16(gB1 + k0, &ldsB[e1]);
    gload_lds16(gB2 + k0, &ldsB[e2]);
    __syncthreads();   // compiler drains vmcnt before s_barrier

    short8 af[4], bf[4];
#pragma unroll
    for (int m = 0; m < 4; ++m)
      af[m] = *(const short8*)&ldsA[(wr * 64 + m * 16 + lr) * 32 + kq * 8];
#pragma unroll
    for (int n = 0; n < 4; ++n)
      bf[n] = *(const short8*)&ldsB[(wc * 64 + n * 16 + lr) * 32 + kq * 8];
#pragma unroll
    for (int m = 0; m < 4; ++m)
#pragma unroll
      for (int n = 0; n < 4; ++n)
        acc[m][n] = __builtin_amdgcn_mfma_f32_16x16x32_bf16(af[m], bf[n], acc[m][n], 0, 0, 0);
    __syncthreads();
  }

  const int dob = flags & 1, dor = flags & 2, f32o = flags & 4;
  float* Cf = (float*)Cout + (long)blockIdx.z * sC;
  short* Cb = (short*)Cout + (long)blockIdx.z * sC;
  // C/D layout: col = lane&15, row = (lane>>4)*4 + reg   [m89-verified]
  const long r0 = m0 + wr * 64 + kq * 4;
  const long c0 = n0 + wc * 64 + lr;
#pragma unroll
  for (int m = 0; m < 4; ++m)
#pragma unroll
    for (int n = 0; n < 4; ++n) {
      const long c = c0 + n * 16;
      float bv = dob ? bias[c] : 0.f;
#pragma unroll
      for (int i = 0; i < 4; ++i) {
        const long r = r0 + m * 16 + i;
        float v = acc[m][n][i] * alpha + bv;
        if (dor) v = fmaxf(v, 0.f);
        if (f32o) Cf[r * ldc + c] = v;
        else      Cb[r * ldc + c] = f2bf(v);
      }
    }
}

// ---------------- elementwise / utility kernels ----------------

__global__ __launch_bounds__(256) void cast_x_k(const float* __restrict__ X,
                                                short* __restrict__ Xb) {
  int i = blockIdx.x * 256 + threadIdx.x;           // n4 = 2097152 exact
  float4v v = ((const float4v*)X)[i];
  short4v o;
#pragma unroll
  for (int j = 0; j < 4; ++j) o[j] = f2bf(v[j]);
  ((short4v*)Xb)[i] = o;
}

// W (rows x cols, fp32 row-major) -> Wt (cols x rows, bf16)
__global__ __launch_bounds__(256) void twcast_k(const float* __restrict__ W,
                                                short* __restrict__ Wt,
                                                int rows, int cols) {
  __shared__ float tile[32][33];
  int tx = threadIdx.x & 31, ty = threadIdx.x >> 5;
  int c0 = blockIdx.x * 32, r0 = blockIdx.y * 32;
#pragma unroll
  for (int r = ty; r < 32; r += 8)
    tile[r][tx] = W[(long)(r0 + r) * cols + c0 + tx];
  __syncthreads();
#pragma unroll
  for (int r = ty; r < 32; r += 8)
    Wt[(long)(c0 + r) * rows + r0 + tx] = f2bf(tile[tx][r]);
}

__global__ void cbias_k(const float* __restrict__ bq, const float* __restrict__ bk,
                        const float* __restrict__ bv, float* __restrict__ o) {
  int i = blockIdx.x * 256 + threadIdx.x;
  if (i < 1024) o[i] = bq[i];
  else if (i < 2048) o[i] = bk[i - 1024];
  else if (i < 3072) o[i] = bv[i - 2048];
}

// v (inside qkv, cols 2048..3071) -> vT[b][d][t]
__global__ __launch_bounds__(256) void tv_k(const short* __restrict__ qkv,
                                            short* __restrict__ vT) {
  __shared__ short tile[32][33];
  int b = blockIdx.z;
  int tx = threadIdx.x & 31, ty = threadIdx.x >> 5;
  int d0 = blockIdx.x * 32, t0 = blockIdx.y * 32;
#pragma unroll
  for (int r = ty; r < 32; r += 8)
    tile[r][tx] = qkv[((long)(b * 2048 + t0 + r)) * 3072 + 2048 + d0 + tx];
  __syncthreads();
#pragma unroll
  for (int r = ty; r < 32; r += 8)
    vT[(long)b * 2097152 + (long)(d0 + r) * 2048 + t0 + tx] = tile[tx][r];
}

// in-place row softmax over 2048 bf16 elements, one block per row
__global__ __launch_bounds__(256) void softmax_k(short* __restrict__ s) {
  __shared__ float red[8];
  long r = blockIdx.x;
  short* p = s + r * 2048;
  int tid = threadIdx.x;
  short8 raw = *(short8*)&p[tid * 8];
  float v[8];
  float mx = -1e30f;
#pragma unroll
  for (int j = 0; j < 8; ++j) { v[j] = bf2f(raw[j]); mx = fmaxf(mx, v[j]); }
#pragma unroll
  for (int o = 32; o; o >>= 1) mx = fmaxf(mx, __shfl_xor(mx, o));
  if ((tid & 63) == 0) red[tid >> 6] = mx;
  __syncthreads();
  mx = fmaxf(fmaxf(red[0], red[1]), fmaxf(red[2], red[3]));
  float sum = 0.f;
#pragma unroll
  for (int j = 0; j < 8; ++j) { v[j] = __expf(v[j] - mx); sum += v[j]; }
#pragma unroll
  for (int o = 32; o; o >>= 1) sum += __shfl_xor(sum, o);
  if ((tid & 63) == 0) red[4 + (tid >> 6)] = sum;
  __syncthreads();
  float inv = 1.f / (red[4] + red[5] + red[6] + red[7]);
  short8 o8;
#pragma unroll
  for (int j = 0; j < 8; ++j) o8[j] = f2bf(v[j] * inv);
  *(short8*)&p[tid * 8] = o8;
}

// out = LN(a + b) * g + be ; writes fp32 (and optional bf16 copy). One block per row (D=1024).
__global__ __launch_bounds__(256) void addln_k(const float* __restrict__ a,
                                               const float* __restrict__ b,
                                               const float* __restrict__ g,
                                               const float* __restrict__ be,
                                               float* __restrict__ outf,
                                               short* __restrict__ outb) {
  __shared__ float red[8];
  long r = blockIdx.x;
  int tid = threadIdx.x;
  float4v va = ((const float4v*)(a + r * 1024))[tid];
  float4v vb = ((const float4v*)(b + r * 1024))[tid];
  float x[4]; float s = 0.f;
#pragma unroll
  for (int j = 0; j < 4; ++j) { x[j] = va[j] + vb[j]; s += x[j]; }
#pragma unroll
  for (int o = 32; o; o >>= 1) s += __shfl_xor(s, o);
  if ((tid & 63) == 0) red[tid >> 6] = s;
  __syncthreads();
  float mu = (red[0] + red[1] + red[2] + red[3]) * (1.f / 1024.f);
  float ss = 0.f;
#pragma unroll
  for (int j = 0; j < 4; ++j) { float d = x[j] - mu; ss += d * d; }
#pragma unroll
  for (int o = 32; o; o >>= 1) ss += __shfl_xor(ss, o);
  if ((tid & 63) == 0) red[4 + (tid >> 6)] = ss;
  __syncthreads();
  float var = (red[4] + red[5] + red[6] + red[7]) * (1.f / 1024.f);
  float rstd = rsqrtf(var + 1e-5f);
  float4v vg = ((const float4v*)g)[tid];
  float4v vbe = ((const float4v*)be)[tid];
  float4v y;
#pragma unroll
  for (int j = 0; j < 4; ++j) y[j] = (x[j] - mu) * rstd * vg[j] + vbe[j];
  ((float4v*)(outf + r * 1024))[tid] = y;
  if (outb) {
    short4v ob;
#pragma unroll
    for (int j = 0; j < 4; ++j) ob[j] = f2bf(y[j]);
    ((short4v*)(outb + r * 1024))[tid] = ob;
  }
}

// ---------------- host launcher ----------------

extern "C" void kernel_launch(void* const* d_in, const int* in_sizes, int n_in,
                              void* d_out, int out_size, void* d_ws, size_t ws_size,
                              hipStream_t stream) {
  const float* X  = (const float*)d_in[0];
  const float* Wq = (const float*)d_in[1];
  const float* bq = (const float*)d_in[2];
  const float* Wk = (const float*)d_in[3];
  const float* bk = (const float*)d_in[4];
  const float* Wv = (const float*)d_in[5];
  const float* bv = (const float*)d_in[6];
  const float* W1 = (const float*)d_in[7];
  const float* b1 = (const float*)d_in[8];
  const float* W2 = (const float*)d_in[9];
  const float* b2 = (const float*)d_in[10];
  const float* W3 = (const float*)d_in[11];
  const float* b3 = (const float*)d_in[12];
  const float* g1  = (const float*)d_in[13];
  const float* be1 = (const float*)d_in[14];
  const float* g2  = (const float*)d_in[15];
  const float* be2 = (const float*)d_in[16];

  char* ws = (char*)d_ws;
  // ---- workspace layout (bytes); peak = 130,035,712 with aliasing ----
  short* Xb     = (short*)(ws + 0);           // 16,777,216  (dead after QKV -> hb)
  short* Wqkvt  = (short*)(ws + 16777216);    //  6,291,456
  short* W1t    = (short*)(ws + 23068672);    //  2,097,152
  short* W2t    = (short*)(ws + 25165824);    //  2,097,152
  short* W3t    = (short*)(ws + 27262976);    //  2,097,152
  float* bqkv   = (float*)(ws + 29360128);    //     12,288
  short* qkv    = (short*)(ws + 29372416);    // 50,331,648  (dead after vT/scores)
  short* vT     = (short*)(ws + 79704064);    // 16,777,216  (dead after ctx)
  short* scores = (short*)(ws + 96481280);    // 33,554,432  (in-place softmax; dead after ctx)
  float* ctx    = (float*)(ws + 29372416);    // 33,554,432  over q,k (dead)
  float* h      = (float*)(ws + 96481280);    // 33,554,432  over scores (dead)
  short* hb     = (short*)(ws + 0);           // 16,777,216  over Xb (dead)
  short* m1     = (short*)(ws + 29372416);    // over ctx lower (dead after LN1)
  short* m2     = (short*)(ws + 46149632);    // over ctx upper
  float* m3     = (float*)(ws + 62926848);    // 33,554,432 over qkv tail (dead), ends 96,481,280
  float* out    = (float*)d_out;

  // 1) casts
  cast_x_k<<<8192, 256, 0, stream>>>(X, Xb);
  twcast_k<<<dim3(32, 32), 256, 0, stream>>>(Wq, Wqkvt + 0,       1024, 1024);
  twcast_k<<<dim3(32, 32), 256, 0, stream>>>(Wk, Wqkvt + 1048576, 1024, 1024);
  twcast_k<<<dim3(32, 32), 256, 0, stream>>>(Wv, Wqkvt + 2097152, 1024, 1024);
  twcast_k<<<dim3(32, 32), 256, 0, stream>>>(W1, W1t, 1024, 1024);
  twcast_k<<<dim3(32, 32), 256, 0, stream>>>(W2, W2t, 1024, 1024);
  twcast_k<<<dim3(32, 32), 256, 0, stream>>>(W3, W3t, 1024, 1024);
  cbias_k<<<12, 256, 0, stream>>>(bq, bk, bv, bqkv);

  // 2) fused QKV: [8192,1024] @ [1024,3072] -> qkv bf16 [8192,3072]
  gemm_nt<<<dim3(64, 24, 1), 256, 0, stream>>>(
      Xb, Wqkvt, bqkv, 1.0f, qkv, 1024, 1024, 1024, 3072, 0, 0, 0, /*bias*/1);

  // 3) v -> vT[b][d][t]
  tv_k<<<dim3(32, 64, 4), 256, 0, stream>>>(qkv, vT);

  // 4) scores[b] = q kT / 32 -> bf16 [2048,2048] per batch
  gemm_nt<<<dim3(16, 16, 4), 256, 0, stream>>>(
      qkv, qkv + 1024, nullptr, 0.03125f, scores, 1024, 3072, 3072, 2048,
      (long)2048 * 3072, (long)2048 * 3072, (long)2048 * 2048, 0);

  // 5) softmax rows in place
  softmax_k<<<8192, 256, 0, stream>>>(scores);

  // 6) ctx[b] = attn @ v  (fp32 out, [8192,1024] flattened)
  gemm_nt<<<dim3(16, 8, 4), 256, 0, stream>>>(
      scores, vT, nullptr, 1.0f, ctx, 2048, 2048, 2048, 1024,
      (long)2048 * 2048, (long)1024 * 2048, (long)2048 * 1024, /*fp32*/4);

  // 7) h = LN(ctx + X); also hb bf16
  addln_k<<<8192, 256, 0, stream>>>(ctx, X, g1, be1, h, hb);

  // 8) MLP
  gemm_nt<<<dim3(64, 8, 1), 256, 0, stream>>>(
      hb, W1t, b1, 1.0f, m1, 1024, 1024, 1024, 1024, 0, 0, 0, /*bias|relu*/3);
  gemm_nt<<<dim3(64, 8, 1), 256, 0, stream>>>(
      m1, W2t, b2, 1.0f, m2, 1024, 1024, 1024, 1024, 0, 0, 0, /*bias|relu*/3);
  gemm_nt<<<dim3(64, 8, 1), 256, 0, stream>>>(
      m2, W3t, b3, 1.0f, m3, 1024, 1024, 1024, 1024, 0, 0, 0, /*bias|fp32*/5);

  // 9) out = LN(m3 + h)
  addln_k<<<8192, 256, 0, stream>>>(m3, h, g2, be2, out, nullptr);
}

// Round 2
// 390.130 us; speedup vs baseline: 1.0120x; 1.0120x over previous
//
#include <hip/hip_runtime.h>
#include <hip/hip_bf16.h>

// TransformerBlock: N=4, T=2048, D=1024. All GEMMs bf16 MFMA 16x16x32, NT form.
// GEMM = 256x256 tile, BK=64, 8 waves (2x4), 8-phase counted-vmcnt schedule,
// XOR-swizzled LDS (chunk ^= row&7 at 16B granularity), setprio around MFMA.

typedef __attribute__((ext_vector_type(8))) short short8;
typedef __attribute__((ext_vector_type(4))) short short4v;
typedef __attribute__((ext_vector_type(4))) float float4v;

#define DEVI static __device__ __forceinline__

DEVI float bf2f(short s) {
  union { unsigned u; float f; } c;
  c.u = ((unsigned)(unsigned short)s) << 16;
  return c.f;
}
DEVI short f2bf(float f) {
  union { __hip_bfloat16 h; short s; } c;
  c.h = __float2bfloat16(f);
  return c.s;
}
DEVI void gload_lds16(const void* g, void* l) {
  __builtin_amdgcn_global_load_lds(
      (const __attribute__((address_space(1))) void*)g,
      (__attribute__((address_space(3))) void*)l, 16, 0, 0);
}

#define MFMA16 __builtin_amdgcn_mfma_f32_16x16x32_bf16

// ---------------- 256x256 8-phase GEMM ----------------
// flags: 1=bias, 2=relu, 4=fp32 output (else bf16)
__global__ __launch_bounds__(512, 2) void gemm8p(
    const short* __restrict__ A, const short* __restrict__ B,
    const float* __restrict__ bias, float alpha, void* __restrict__ Cout,
    int K, int lda, int ldb, int ldc,
    long sA, long sB, long sC, int flags)
{
  // LDS: A tiles [2][256 rows][64 cols] bf16 at bytes 0..65535,
  //      B tiles same at 65536..131071. Row = 128B; 16B chunk swizzle c^=(row&7).
  __shared__ __attribute__((aligned(16))) short lds[65536];

  const int tid  = threadIdx.x;
  const int lane = tid & 63;
  const int wid  = tid >> 6;
  const int wm = wid >> 2, wn = wid & 3;   // wave grid 2(M) x 4(N); wave owns 128x64
  const int lr = lane & 15;
  const int kq = lane >> 4;

  const long m0 = (long)blockIdx.x * 256;
  const long n0 = (long)blockIdx.y * 256;
  const short* Ab = A + (long)blockIdx.z * sA;
  const short* Bb = B + (long)blockIdx.z * sB;

  // swizzled source column offset (elements) for staging
  const int sc8 = (((tid & 7) ^ ((tid >> 3) & 7)) << 3);

  // stage unit uA<half>: rows {half*64 + q*128 + tid>>3}, dest linear per wave
  auto stageA = [&](int kt, int half) {
    char* buf = (char*)lds + (kt & 1) * 32768;
    const long k0 = (long)kt * 64 + sc8;
#pragma unroll
    for (int q = 0; q < 2; ++q) {
      const int row = half * 64 + q * 128 + (tid >> 3);
      gload_lds16(Ab + (m0 + row) * (long)lda + k0,
                  buf + half * 8192 + q * 16384 + tid * 16);
    }
  };
  // stage unit uB<half>: rows {half*32 + (q*2 + tid>>8)*64 + ((tid>>3)&31)}
  auto stageB = [&](int kt, int half) {
    char* buf = (char*)lds + 65536 + (kt & 1) * 32768;
    const long k0 = (long)kt * 64 + sc8;
#pragma unroll
    for (int q = 0; q < 2; ++q) {
      const int row = half * 32 + (q * 2 + (tid >> 8)) * 64 + ((tid >> 3) & 31);
      gload_lds16(Bb + (n0 + row) * (long)ldb + k0,
                  buf + half * 4096 + q * 16384 + (tid >> 8) * 8192 + (tid & 255) * 16);
    }
  };

  auto rdA = [&](int kt, int fm, int kk) -> short8 {
    const char* buf = (const char*)lds + (kt & 1) * 32768;
    const int row = wm * 128 + fm * 16 + lr;
    const int off = row * 128 + ((((kk << 2) + kq) ^ (lr & 7)) << 4);
    return *(const short8*)(buf + off);
  };
  auto rdB = [&](int kt, int fn, int kk) -> short8 {
    const char* buf = (const char*)lds + 65536 + (kt & 1) * 32768;
    const int row = wn * 64 + fn * 16 + lr;
    const int off = row * 128 + ((((kk << 2) + kq) ^ (lr & 7)) << 4);
    return *(const short8*)(buf + off);
  };

  float4v acc[8][4];
#pragma unroll
  for (int m = 0; m < 8; ++m)
#pragma unroll
    for (int n = 0; n < 4; ++n)
#pragma unroll
      for (int i = 0; i < 4; ++i) acc[m][n][i] = 0.f;

  const int NT = K >> 6;

  // prologue: tile0 complete + uA0/uB0 of tile1; keep 4 loads in flight
  stageA(0, 0); stageB(0, 0); stageB(0, 1); stageA(0, 1);
  stageA(1, 0); stageB(1, 0);
  asm volatile("s_waitcnt vmcnt(4)" ::: "memory");
  __builtin_amdgcn_s_barrier();

  short8 a0[4][2], a1[4][2], b0[2][2], b1[2][2];

  for (int t = 0; t < NT; ++t) {
    // ---- P1: read A-low quarter + B-low quarter; stage uB1(t+1); MFMA Q00
#pragma unroll
    for (int m = 0; m < 4; ++m) { a0[m][0] = rdA(t, m, 0); a0[m][1] = rdA(t, m, 1); }
#pragma unroll
    for (int n = 0; n < 2; ++n) { b0[n][0] = rdB(t, n, 0); b0[n][1] = rdB(t, n, 1); }
    if (t + 1 < NT) stageB(t + 1, 1);
    asm volatile("s_waitcnt lgkmcnt(8)" ::: "memory");
    __builtin_amdgcn_s_barrier();
    asm volatile("s_waitcnt lgkmcnt(0)" ::: "memory");
    __builtin_amdgcn_sched_barrier(0);
    __builtin_amdgcn_s_setprio(1);
#pragma unroll
    for (int m = 0; m < 4; ++m)
#pragma unroll
      for (int n = 0; n < 2; ++n)
#pragma unroll
        for (int kk = 0; kk < 2; ++kk)
          acc[m][n] = MFMA16(a0[m][kk], b0[n][kk], acc[m][n], 0, 0, 0);
    __builtin_amdgcn_s_setprio(0);
    __builtin_amdgcn_s_barrier();

    // ---- P2: read B-high quarter; stage uA1(t+1); MFMA Q01
#pragma unroll
    for (int n = 0; n < 2; ++n) { b1[n][0] = rdB(t, n + 2, 0); b1[n][1] = rdB(t, n + 2, 1); }
    if (t + 1 < NT) stageA(t + 1, 1);
    __builtin_amdgcn_s_barrier();
    asm volatile("s_waitcnt lgkmcnt(0)" ::: "memory");
    __builtin_amdgcn_sched_barrier(0);
    __builtin_amdgcn_s_setprio(1);
#pragma unroll
    for (int m = 0; m < 4; ++m)
#pragma unroll
      for (int n = 0; n < 2; ++n)
#pragma unroll
        for (int kk = 0; kk < 2; ++kk)
          acc[m][n + 2] = MFMA16(a0[m][kk], b1[n][kk], acc[m][n + 2], 0, 0, 0);
    __builtin_amdgcn_s_setprio(0);
    __builtin_amdgcn_s_barrier();

    // ---- P3: read A-high quarter; stage uA0(t+2); MFMA Q10
#pragma unroll
    for (int m = 0; m < 4; ++m) { a1[m][0] = rdA(t, m + 4, 0); a1[m][1] = rdA(t, m + 4, 1); }
    if (t + 2 < NT) stageA(t + 2, 0);
    __builtin_amdgcn_s_barrier();
    asm volatile("s_waitcnt lgkmcnt(0)" ::: "memory");
    __builtin_amdgcn_sched_barrier(0);
    __builtin_amdgcn_s_setprio(1);
#pragma unroll
    for (int m = 0; m < 4; ++m)
#pragma unroll
      for (int n = 0; n < 2; ++n)
#pragma unroll
        for (int kk = 0; kk < 2; ++kk)
          acc[m + 4][n] = MFMA16(a1[m][kk], b0[n][kk], acc[m + 4][n], 0, 0, 0);
    __builtin_amdgcn_s_setprio(0);
    __builtin_amdgcn_s_barrier();

    // ---- P4: stage uB0(t+2); MFMA Q11; counted-vmcnt checkpoint
    if (t + 2 < NT) stageB(t + 2, 0);
    __builtin_amdgcn_s_barrier();
    __builtin_amdgcn_sched_barrier(0);
    __builtin_amdgcn_s_setprio(1);
#pragma unroll
    for (int m = 0; m < 4; ++m)
#pragma unroll
      for (int n = 0; n < 2; ++n)
#pragma unroll
        for (int kk = 0; kk < 2; ++kk)
          acc[m + 4][n + 2] = MFMA16(a1[m][kk], b1[n][kk], acc[m + 4][n + 2], 0, 0, 0);
    __builtin_amdgcn_s_setprio(0);
    if (t + 2 < NT) { asm volatile("s_waitcnt vmcnt(4)" ::: "memory"); }
    else            { asm volatile("s_waitcnt vmcnt(0)" ::: "memory"); }
    __builtin_amdgcn_s_barrier();
  }

  // ---- epilogue
  const int dob = flags & 1, dor = flags & 2, f32o = flags & 4;
  float* Cf = (float*)Cout + (long)blockIdx.z * sC;
  short* Cb = (short*)Cout + (long)blockIdx.z * sC;
  const long r0 = m0 + wm * 128 + kq * 4;
  const long c0 = n0 + wn * 64 + lr;
#pragma unroll
  for (int m = 0; m < 8; ++m)
#pragma unroll
    for (int n = 0; n < 4; ++n) {
      const long c = c0 + n * 16;
      float bv = dob ? bias[c] : 0.f;
#pragma unroll
      for (int i = 0; i < 4; ++i) {
        const long r = r0 + m * 16 + i;
        float v = acc[m][n][i] * alpha + bv;
        if (dor) v = fmaxf(v, 0.f);
        if (f32o) Cf[r * ldc + c] = v;
        else      Cb[r * ldc + c] = f2bf(v);
      }
    }
}

// ---------------- elementwise / utility kernels ----------------

__global__ __launch_bounds__(256) void cast_x_k(const float* __restrict__ X,
                                                short* __restrict__ Xb) {
  int i = blockIdx.x * 256 + threadIdx.x;
  float4v v = ((const float4v*)X)[i];
  short4v o;
#pragma unroll
  for (int j = 0; j < 4; ++j) o[j] = f2bf(v[j]);
  ((short4v*)Xb)[i] = o;
}

__global__ __launch_bounds__(256) void twcast_k(const float* __restrict__ W,
                                                short* __restrict__ Wt,
                                                int rows, int cols) {
  __shared__ float tile[32][33];
  int tx = threadIdx.x & 31, ty = threadIdx.x >> 5;
  int c0 = blockIdx.x * 32, r0 = blockIdx.y * 32;
#pragma unroll
  for (int r = ty; r < 32; r += 8)
    tile[r][tx] = W[(long)(r0 + r) * cols + c0 + tx];
  __syncthreads();
#pragma unroll
  for (int r = ty; r < 32; r += 8)
    Wt[(long)(c0 + r) * rows + r0 + tx] = f2bf(tile[tx][r]);
}

__global__ void cbias_k(const float* __restrict__ bq, const float* __restrict__ bk,
                        const float* __restrict__ bv, float* __restrict__ o) {
  int i = blockIdx.x * 256 + threadIdx.x;
  if (i < 1024) o[i] = bq[i];
  else if (i < 2048) o[i] = bk[i - 1024];
  else if (i < 3072) o[i] = bv[i - 2048];
}

__global__ __launch_bounds__(256) void tv_k(const short* __restrict__ qkv,
                                            short* __restrict__ vT) {
  __shared__ short tile[32][33];
  int b = blockIdx.z;
  int tx = threadIdx.x & 31, ty = threadIdx.x >> 5;
  int d0 = blockIdx.x * 32, t0 = blockIdx.y * 32;
#pragma unroll
  for (int r = ty; r < 32; r += 8)
    tile[r][tx] = qkv[((long)(b * 2048 + t0 + r)) * 3072 + 2048 + d0 + tx];
  __syncthreads();
#pragma unroll
  for (int r = ty; r < 32; r += 8)
    vT[(long)b * 2097152 + (long)(d0 + r) * 2048 + t0 + tx] = tile[tx][r];
}

__global__ __launch_bounds__(256) void softmax_k(short* __restrict__ s) {
  __shared__ float red[8];
  long r = blockIdx.x;
  short* p = s + r * 2048;
  int tid = threadIdx.x;
  short8 raw = *(short8*)&p[tid * 8];
  float v[8];
  float mx = -1e30f;
#pragma unroll
  for (int j = 0; j < 8; ++j) { v[j] = bf2f(raw[j]); mx = fmaxf(mx, v[j]); }
#pragma unroll
  for (int o = 32; o; o >>= 1) mx = fmaxf(mx, __shfl_xor(mx, o));
  if ((tid & 63) == 0) red[tid >> 6] = mx;
  __syncthreads();
  mx = fmaxf(fmaxf(red[0], red[1]), fmaxf(red[2], red[3]));
  float sum = 0.f;
#pragma unroll
  for (int j = 0; j < 8; ++j) { v[j] = __expf(v[j] - mx); sum += v[j]; }
#pragma unroll
  for (int o = 32; o; o >>= 1) sum += __shfl_xor(sum, o);
  if ((tid & 63) == 0) red[4 + (tid >> 6)] = sum;
  __syncthreads();
  float inv = 1.f / (red[4] + red[5] + red[6] + red[7]);
  short8 o8;
#pragma unroll
  for (int j = 0; j < 8; ++j) o8[j] = f2bf(v[j] * inv);
  *(short8*)&p[tid * 8] = o8;
}

__global__ __launch_bounds__(256) void addln_k(const float* __restrict__ a,
                                               const float* __restrict__ b,
                                               const float* __restrict__ g,
                                               const float* __restrict__ be,
                                               float* __restrict__ outf,
                                               short* __restrict__ outb) {
  __shared__ float red[8];
  long r = blockIdx.x;
  int tid = threadIdx.x;
  float4v va = ((const float4v*)(a + r * 1024))[tid];
  float4v vb = ((const float4v*)(b + r * 1024))[tid];
  float x[4]; float s = 0.f;
#pragma unroll
  for (int j = 0; j < 4; ++j) { x[j] = va[j] + vb[j]; s += x[j]; }
#pragma unroll
  for (int o = 32; o; o >>= 1) s += __shfl_xor(s, o);
  if ((tid & 63) == 0) red[tid >> 6] = s;
  __syncthreads();
  float mu = (red[0] + red[1] + red[2] + red[3]) * (1.f / 1024.f);
  float ss = 0.f;
#pragma unroll
  for (int j = 0; j < 4; ++j) { float d = x[j] - mu; ss += d * d; }
#pragma unroll
  for (int o = 32; o; o >>= 1) ss += __shfl_xor(ss, o);
  if ((tid & 63) == 0) red[4 + (tid >> 6)] = ss;
  __syncthreads();
  float var = (red[4] + red[5] + red[6] + red[7]) * (1.f / 1024.f);
  float rstd = rsqrtf(var + 1e-5f);
  float4v vg = ((const float4v*)g)[tid];
  float4v vbe = ((const float4v*)be)[tid];
  float4v y;
#pragma unroll
  for (int j = 0; j < 4; ++j) y[j] = (x[j] - mu) * rstd * vg[j] + vbe[j];
  ((float4v*)(outf + r * 1024))[tid] = y;
  if (outb) {
    short4v ob;
#pragma unroll
    for (int j = 0; j < 4; ++j) ob[j] = f2bf(y[j]);
    ((short4v*)(outb + r * 1024))[tid] = ob;
  }
}

// ---------------- host launcher ----------------

extern "C" void kernel_launch(void* const* d_in, const int* in_sizes, int n_in,
                              void* d_out, int out_size, void* d_ws, size_t ws_size,
                              hipStream_t stream) {
  const float* X  = (const float*)d_in[0];
  const float* Wq = (const float*)d_in[1];
  const float* bq = (const float*)d_in[2];
  const float* Wk = (const float*)d_in[3];
  const float* bk = (const float*)d_in[4];
  const float* Wv = (const float*)d_in[5];
  const float* bv = (const float*)d_in[6];
  const float* W1 = (const float*)d_in[7];
  const float* b1 = (const float*)d_in[8];
  const float* W2 = (const float*)d_in[9];
  const float* b2 = (const float*)d_in[10];
  const float* W3 = (const float*)d_in[11];
  const float* b3 = (const float*)d_in[12];
  const float* g1  = (const float*)d_in[13];
  const float* be1 = (const float*)d_in[14];
  const float* g2  = (const float*)d_in[15];
  const float* be2 = (const float*)d_in[16];

  char* ws = (char*)d_ws;
  short* Xb     = (short*)(ws + 0);
  short* Wqkvt  = (short*)(ws + 16777216);
  short* W1t    = (short*)(ws + 23068672);
  short* W2t    = (short*)(ws + 25165824);
  short* W3t    = (short*)(ws + 27262976);
  float* bqkv   = (float*)(ws + 29360128);
  short* qkv    = (short*)(ws + 29372416);
  short* vT     = (short*)(ws + 79704064);
  short* scores = (short*)(ws + 96481280);
  float* ctx    = (float*)(ws + 29372416);
  float* h      = (float*)(ws + 96481280);
  short* hb     = (short*)(ws + 0);
  short* m1     = (short*)(ws + 29372416);
  short* m2     = (short*)(ws + 46149632);
  float* m3     = (float*)(ws + 62926848);
  float* out    = (float*)d_out;

  cast_x_k<<<8192, 256, 0, stream>>>(X, Xb);
  twcast_k<<<dim3(32, 32), 256, 0, stream>>>(Wq, Wqkvt + 0,       1024, 1024);
  twcast_k<<<dim3(32, 32), 256, 0, stream>>>(Wk, Wqkvt + 1048576, 1024, 1024);
  twcast_k<<<dim3(32, 32), 256, 0, stream>>>(Wv, Wqkvt + 2097152, 1024, 1024);
  twcast_k<<<dim3(32, 32), 256, 0, stream>>>(W1, W1t, 1024, 1024);
  twcast_k<<<dim3(32, 32), 256, 0, stream>>>(W2, W2t, 1024, 1024);
  twcast_k<<<dim3(32, 32), 256, 0, stream>>>(W3, W3t, 1024, 1024);
  cbias_k<<<12, 256, 0, stream>>>(bq, bk, bv, bqkv);

  // QKV: [8192,1024] x [3072,1024]^T -> bf16 [8192,3072]
  gemm8p<<<dim3(32, 12, 1), 512, 0, stream>>>(
      Xb, Wqkvt, bqkv, 1.0f, qkv, 1024, 1024, 1024, 3072, 0, 0, 0, 1);

  tv_k<<<dim3(32, 64, 4), 256, 0, stream>>>(qkv, vT);

  // scores[b] = q k^T / 32 -> bf16 [2048,2048]
  gemm8p<<<dim3(8, 8, 4), 512, 0, stream>>>(
      qkv, qkv + 1024, nullptr, 0.03125f, scores, 1024, 3072, 3072, 2048,
      (long)2048 * 3072, (long)2048 * 3072, (long)2048 * 2048, 0);

  softmax_k<<<8192, 256, 0, stream>>>(scores);

  // ctx[b] = attn @ v (fp32 out)
  gemm8p<<<dim3(8, 4, 4), 512, 0, stream>>>(
      scores, vT, nullptr, 1.0f, ctx, 2048, 2048, 2048, 1024,
      (long)2048 * 2048, (long)1024 * 2048, (long)2048 * 1024, 4);

  addln_k<<<8192, 256, 0, stream>>>(ctx, X, g1, be1, h, hb);

  gemm8p<<<dim3(32, 4, 1), 512, 0, stream>>>(
      hb, W1t, b1, 1.0f, m1, 1024, 1024, 1024, 1024, 0, 0, 0, 3);
  gemm8p<<<dim3(32, 4, 1), 512, 0, stream>>>(
      m1, W2t, b2, 1.0f, m2, 1024, 1024, 1024, 1024, 0, 0, 0, 3);
  gemm8p<<<dim3(32, 4, 1), 512, 0, stream>>>(
      m2, W3t, b3, 1.0f, m3, 1024, 1024, 1024, 1024, 0, 0, 0, 5);

  addln_k<<<8192, 256, 0, stream>>>(m3, h, g2, be2, out, nullptr);
}

// Round 3
// 374.614 us; speedup vs baseline: 1.0539x; 1.0414x over previous
//
#include <hip/hip_runtime.h>
#include <hip/hip_bf16.h>

// TransformerBlock: N=4, T=2048, D=1024. All GEMMs bf16 MFMA 16x16x32, NT form.
// GEMM = 256x256 tile, BK=64, 8 waves (2x4), 4 phases/K-tile with ONE barrier
// per phase (race-analyzed), counted vmcnt (never 0 mid-loop), XOR-swizzled LDS,
// setprio around MFMA, bijective XCD-aware block swizzle.

typedef __attribute__((ext_vector_type(8))) short short8;
typedef __attribute__((ext_vector_type(4))) short short4v;
typedef __attribute__((ext_vector_type(4))) float float4v;

#define DEVI static __device__ __forceinline__

DEVI float bf2f(short s) {
  union { unsigned u; float f; } c;
  c.u = ((unsigned)(unsigned short)s) << 16;
  return c.f;
}
DEVI short f2bf(float f) {
  union { __hip_bfloat16 h; short s; } c;
  c.h = __float2bfloat16(f);
  return c.s;
}
DEVI void gload_lds16(const void* g, void* l) {
  __builtin_amdgcn_global_load_lds(
      (const __attribute__((address_space(1))) void*)g,
      (__attribute__((address_space(3))) void*)l, 16, 0, 0);
}

#define MFMA16 __builtin_amdgcn_mfma_f32_16x16x32_bf16
#define CFENCE asm volatile("" ::: "memory")

// ---------------- 256x256 GEMM, 4 phases/K-tile, 1 barrier/phase ----------------
// flags: 1=bias, 2=relu, 4=fp32 output (else bf16)
__global__ __launch_bounds__(512, 2) void gemm8p(
    const short* __restrict__ A, const short* __restrict__ B,
    const float* __restrict__ bias, float alpha, void* __restrict__ Cout,
    int K, int lda, int ldb, int ldc,
    long sA, long sB, long sC, int flags, int gx, int gy)
{
  __shared__ __attribute__((aligned(16))) short lds[65536];

  // bijective XCD swizzle (m204): consecutive logical ids -> same XCD chunk
  const int nwg = gridDim.x;
  const int orig = blockIdx.x;
  const int q8 = nwg >> 3, r8 = nwg & 7;
  const int xcd = orig & 7, lin = orig >> 3;
  const int wgid = (xcd < r8 ? xcd * (q8 + 1) : r8 * (q8 + 1) + (xcd - r8) * q8) + lin;
  const int bz = wgid / (gx * gy);
  const int rem = wgid - bz * gx * gy;
  const int by = rem / gx;
  const int bx = rem - by * gx;

  const int tid  = threadIdx.x;
  const int lane = tid & 63;
  const int wid  = tid >> 6;
  const int wm = wid >> 2, wn = wid & 3;   // 2(M) x 4(N); wave owns 128x64
  const int lr = lane & 15;
  const int kq = lane >> 4;

  const long m0 = (long)bx * 256;
  const long n0 = (long)by * 256;
  const short* Ab = A + (long)bz * sA;
  const short* Bb = B + (long)bz * sB;

  const int sc8 = (((tid & 7) ^ ((tid >> 3) & 7)) << 3);

  auto stageA = [&](int kt, int half) {
    char* buf = (char*)lds + (kt & 1) * 32768;
    const long k0 = (long)kt * 64 + sc8;
#pragma unroll
    for (int q = 0; q < 2; ++q) {
      const int row = half * 64 + q * 128 + (tid >> 3);
      gload_lds16(Ab + (m0 + row) * (long)lda + k0,
                  buf + half * 8192 + q * 16384 + tid * 16);
    }
  };
  auto stageB = [&](int kt, int half) {
    char* buf = (char*)lds + 65536 + (kt & 1) * 32768;
    const long k0 = (long)kt * 64 + sc8;
#pragma unroll
    for (int q = 0; q < 2; ++q) {
      const int row = half * 32 + (q * 2 + (tid >> 8)) * 64 + ((tid >> 3) & 31);
      gload_lds16(Bb + (n0 + row) * (long)ldb + k0,
                  buf + half * 4096 + q * 16384 + (tid >> 8) * 8192 + (tid & 255) * 16);
    }
  };

  auto rdA = [&](int kt, int fm, int kk) -> short8 {
    const char* buf = (const char*)lds + (kt & 1) * 32768;
    const int row = wm * 128 + fm * 16 + lr;
    const int off = row * 128 + ((((kk << 2) + kq) ^ (lr & 7)) << 4);
    return *(const short8*)(buf + off);
  };
  auto rdB = [&](int kt, int fn, int kk) -> short8 {
    const char* buf = (const char*)lds + 65536 + (kt & 1) * 32768;
    const int row = wn * 64 + fn * 16 + lr;
    const int off = row * 128 + ((((kk << 2) + kq) ^ (lr & 7)) << 4);
    return *(const short8*)(buf + off);
  };

  float4v acc[8][4];
#pragma unroll
  for (int m = 0; m < 8; ++m)
#pragma unroll
    for (int n = 0; n < 4; ++n)
#pragma unroll
      for (int i = 0; i < 4; ++i) acc[m][n][i] = 0.f;

  const int NT = K >> 6;

  // prologue: tile0 complete + uA0/uB0 of tile1; keep 4 loads in flight
  stageA(0, 0); stageB(0, 0); stageB(0, 1); stageA(0, 1);
  stageA(1, 0); stageB(1, 0);
  asm volatile("s_waitcnt vmcnt(4)" ::: "memory");
  __builtin_amdgcn_s_barrier();
  CFENCE;

  short8 a0[4][2], a1[4][2], b0[2][2], b1[2][2];

  for (int t = 0; t < NT; ++t) {
    // ---- P1: read A-low + B-low; stage uB1(t+1); MFMA Q00
#pragma unroll
    for (int m = 0; m < 4; ++m) { a0[m][0] = rdA(t, m, 0); a0[m][1] = rdA(t, m, 1); }
#pragma unroll
    for (int n = 0; n < 2; ++n) { b0[n][0] = rdB(t, n, 0); b0[n][1] = rdB(t, n, 1); }
    if (t + 1 < NT) stageB(t + 1, 1);
    __builtin_amdgcn_s_barrier();
    CFENCE;
    asm volatile("s_waitcnt lgkmcnt(0)" ::: "memory");
    __builtin_amdgcn_sched_barrier(0);
    __builtin_amdgcn_s_setprio(1);
#pragma unroll
    for (int m = 0; m < 4; ++m)
#pragma unroll
      for (int n = 0; n < 2; ++n)
#pragma unroll
        for (int kk = 0; kk < 2; ++kk)
          acc[m][n] = MFMA16(a0[m][kk], b0[n][kk], acc[m][n], 0, 0, 0);
    __builtin_amdgcn_s_setprio(0);

    // ---- P2: read B-high; stage uA1(t+1); MFMA Q01
#pragma unroll
    for (int n = 0; n < 2; ++n) { b1[n][0] = rdB(t, n + 2, 0); b1[n][1] = rdB(t, n + 2, 1); }
    if (t + 1 < NT) stageA(t + 1, 1);
    __builtin_amdgcn_s_barrier();
    CFENCE;
    asm volatile("s_waitcnt lgkmcnt(0)" ::: "memory");
    __builtin_amdgcn_sched_barrier(0);
    __builtin_amdgcn_s_setprio(1);
#pragma unroll
    for (int m = 0; m < 4; ++m)
#pragma unroll
      for (int n = 0; n < 2; ++n)
#pragma unroll
        for (int kk = 0; kk < 2; ++kk)
          acc[m][n + 2] = MFMA16(a0[m][kk], b1[n][kk], acc[m][n + 2], 0, 0, 0);
    __builtin_amdgcn_s_setprio(0);

    // ---- P3: read A-high; stage uA0(t+2); MFMA Q10
#pragma unroll
    for (int m = 0; m < 4; ++m) { a1[m][0] = rdA(t, m + 4, 0); a1[m][1] = rdA(t, m + 4, 1); }
    if (t + 2 < NT) stageA(t + 2, 0);
    __builtin_amdgcn_s_barrier();
    CFENCE;
    asm volatile("s_waitcnt lgkmcnt(0)" ::: "memory");
    __builtin_amdgcn_sched_barrier(0);
    __builtin_amdgcn_s_setprio(1);
#pragma unroll
    for (int m = 0; m < 4; ++m)
#pragma unroll
      for (int n = 0; n < 2; ++n)
#pragma unroll
        for (int kk = 0; kk < 2; ++kk)
          acc[m + 4][n] = MFMA16(a1[m][kk], b0[n][kk], acc[m + 4][n], 0, 0, 0);
    __builtin_amdgcn_s_setprio(0);

    // ---- P4: stage uB0(t+2); vmcnt checkpoint; MFMA Q11
    if (t + 2 < NT) stageB(t + 2, 0);
    if (t + 2 < NT) { asm volatile("s_waitcnt vmcnt(4)" ::: "memory"); }
    else            { asm volatile("s_waitcnt vmcnt(0)" ::: "memory"); }
    __builtin_amdgcn_s_barrier();
    CFENCE;
    __builtin_amdgcn_sched_barrier(0);
    __builtin_amdgcn_s_setprio(1);
#pragma unroll
    for (int m = 0; m < 4; ++m)
#pragma unroll
      for (int n = 0; n < 2; ++n)
#pragma unroll
        for (int kk = 0; kk < 2; ++kk)
          acc[m + 4][n + 2] = MFMA16(a1[m][kk], b1[n][kk], acc[m + 4][n + 2], 0, 0, 0);
    __builtin_amdgcn_s_setprio(0);
  }

  // ---- epilogue
  const int dob = flags & 1, dor = flags & 2, f32o = flags & 4;
  float* Cf = (float*)Cout + (long)bz * sC;
  short* Cb = (short*)Cout + (long)bz * sC;
  const long r0 = m0 + wm * 128 + kq * 4;
  const long c0 = n0 + wn * 64 + lr;
#pragma unroll
  for (int m = 0; m < 8; ++m)
#pragma unroll
    for (int n = 0; n < 4; ++n) {
      const long c = c0 + n * 16;
      float bv = dob ? bias[c] : 0.f;
#pragma unroll
      for (int i = 0; i < 4; ++i) {
        const long r = r0 + m * 16 + i;
        float v = acc[m][n][i] * alpha + bv;
        if (dor) v = fmaxf(v, 0.f);
        if (f32o) Cf[r * ldc + c] = v;
        else      Cb[r * ldc + c] = f2bf(v);
      }
    }
}

// ---------------- elementwise / utility kernels ----------------

__global__ __launch_bounds__(256) void cast_x_k(const float* __restrict__ X,
                                                short* __restrict__ Xb) {
  int i = blockIdx.x * 256 + threadIdx.x;
  float4v v = ((const float4v*)X)[i];
  short4v o;
#pragma unroll
  for (int j = 0; j < 4; ++j) o[j] = f2bf(v[j]);
  ((short4v*)Xb)[i] = o;
}

__global__ __launch_bounds__(256) void twcast_k(const float* __restrict__ W,
                                                short* __restrict__ Wt,
                                                int rows, int cols) {
  __shared__ float tile[32][33];
  int tx = threadIdx.x & 31, ty = threadIdx.x >> 5;
  int c0 = blockIdx.x * 32, r0 = blockIdx.y * 32;
#pragma unroll
  for (int r = ty; r < 32; r += 8)
    tile[r][tx] = W[(long)(r0 + r) * cols + c0 + tx];
  __syncthreads();
#pragma unroll
  for (int r = ty; r < 32; r += 8)
    Wt[(long)(c0 + r) * rows + r0 + tx] = f2bf(tile[tx][r]);
}

__global__ void cbias_k(const float* __restrict__ bq, const float* __restrict__ bk,
                        const float* __restrict__ bv, float* __restrict__ o) {
  int i = blockIdx.x * 256 + threadIdx.x;
  if (i < 1024) o[i] = bq[i];
  else if (i < 2048) o[i] = bk[i - 1024];
  else if (i < 3072) o[i] = bv[i - 2048];
}

__global__ __launch_bounds__(256) void tv_k(const short* __restrict__ qkv,
                                            short* __restrict__ vT) {
  __shared__ short tile[32][33];
  int b = blockIdx.z;
  int tx = threadIdx.x & 31, ty = threadIdx.x >> 5;
  int d0 = blockIdx.x * 32, t0 = blockIdx.y * 32;
#pragma unroll
  for (int r = ty; r < 32; r += 8)
    tile[r][tx] = qkv[((long)(b * 2048 + t0 + r)) * 3072 + 2048 + d0 + tx];
  __syncthreads();
#pragma unroll
  for (int r = ty; r < 32; r += 8)
    vT[(long)b * 2097152 + (long)(d0 + r) * 2048 + t0 + tx] = tile[tx][r];
}

__global__ __launch_bounds__(256) void softmax_k(short* __restrict__ s) {
  __shared__ float red[8];
  long r = blockIdx.x;
  short* p = s + r * 2048;
  int tid = threadIdx.x;
  short8 raw = *(short8*)&p[tid * 8];
  float v[8];
  float mx = -1e30f;
#pragma unroll
  for (int j = 0; j < 8; ++j) { v[j] = bf2f(raw[j]); mx = fmaxf(mx, v[j]); }
#pragma unroll
  for (int o = 32; o; o >>= 1) mx = fmaxf(mx, __shfl_xor(mx, o));
  if ((tid & 63) == 0) red[tid >> 6] = mx;
  __syncthreads();
  mx = fmaxf(fmaxf(red[0], red[1]), fmaxf(red[2], red[3]));
  float sum = 0.f;
#pragma unroll
  for (int j = 0; j < 8; ++j) { v[j] = __expf(v[j] - mx); sum += v[j]; }
#pragma unroll
  for (int o = 32; o; o >>= 1) sum += __shfl_xor(sum, o);
  if ((tid & 63) == 0) red[4 + (tid >> 6)] = sum;
  __syncthreads();
  float inv = 1.f / (red[4] + red[5] + red[6] + red[7]);
  short8 o8;
#pragma unroll
  for (int j = 0; j < 8; ++j) o8[j] = f2bf(v[j] * inv);
  *(short8*)&p[tid * 8] = o8;
}

__global__ __launch_bounds__(256) void addln_k(const float* __restrict__ a,
                                               const float* __restrict__ b,
                                               const float* __restrict__ g,
                                               const float* __restrict__ be,
                                               float* __restrict__ outf,
                                               short* __restrict__ outb) {
  __shared__ float red[8];
  long r = blockIdx.x;
  int tid = threadIdx.x;
  float4v va = ((const float4v*)(a + r * 1024))[tid];
  float4v vb = ((const float4v*)(b + r * 1024))[tid];
  float x[4]; float s = 0.f;
#pragma unroll
  for (int j = 0; j < 4; ++j) { x[j] = va[j] + vb[j]; s += x[j]; }
#pragma unroll
  for (int o = 32; o; o >>= 1) s += __shfl_xor(s, o);
  if ((tid & 63) == 0) red[tid >> 6] = s;
  __syncthreads();
  float mu = (red[0] + red[1] + red[2] + red[3]) * (1.f / 1024.f);
  float ss = 0.f;
#pragma unroll
  for (int j = 0; j < 4; ++j) { float d = x[j] - mu; ss += d * d; }
#pragma unroll
  for (int o = 32; o; o >>= 1) ss += __shfl_xor(ss, o);
  if ((tid & 63) == 0) red[4 + (tid >> 6)] = ss;
  __syncthreads();
  float var = (red[4] + red[5] + red[6] + red[7]) * (1.f / 1024.f);
  float rstd = rsqrtf(var + 1e-5f);
  float4v vg = ((const float4v*)g)[tid];
  float4v vbe = ((const float4v*)be)[tid];
  float4v y;
#pragma unroll
  for (int j = 0; j < 4; ++j) y[j] = (x[j] - mu) * rstd * vg[j] + vbe[j];
  ((float4v*)(outf + r * 1024))[tid] = y;
  if (outb) {
    short4v ob;
#pragma unroll
    for (int j = 0; j < 4; ++j) ob[j] = f2bf(y[j]);
    ((short4v*)(outb + r * 1024))[tid] = ob;
  }
}

// ---------------- host launcher ----------------

extern "C" void kernel_launch(void* const* d_in, const int* in_sizes, int n_in,
                              void* d_out, int out_size, void* d_ws, size_t ws_size,
                              hipStream_t stream) {
  const float* X  = (const float*)d_in[0];
  const float* Wq = (const float*)d_in[1];
  const float* bq = (const float*)d_in[2];
  const float* Wk = (const float*)d_in[3];
  const float* bk = (const float*)d_in[4];
  const float* Wv = (const float*)d_in[5];
  const float* bv = (const float*)d_in[6];
  const float* W1 = (const float*)d_in[7];
  const float* b1 = (const float*)d_in[8];
  const float* W2 = (const float*)d_in[9];
  const float* b2 = (const float*)d_in[10];
  const float* W3 = (const float*)d_in[11];
  const float* b3 = (const float*)d_in[12];
  const float* g1  = (const float*)d_in[13];
  const float* be1 = (const float*)d_in[14];
  const float* g2  = (const float*)d_in[15];
  const float* be2 = (const float*)d_in[16];

  char* ws = (char*)d_ws;
  short* Xb     = (short*)(ws + 0);
  short* Wqkvt  = (short*)(ws + 16777216);
  short* W1t    = (short*)(ws + 23068672);
  short* W2t    = (short*)(ws + 25165824);
  short* W3t    = (short*)(ws + 27262976);
  float* bqkv   = (float*)(ws + 29360128);
  short* qkv    = (short*)(ws + 29372416);
  short* vT     = (short*)(ws + 79704064);
  short* scores = (short*)(ws + 96481280);
  float* ctx    = (float*)(ws + 29372416);
  float* h      = (float*)(ws + 96481280);
  short* hb     = (short*)(ws + 0);
  short* m1     = (short*)(ws + 29372416);
  short* m2     = (short*)(ws + 46149632);
  float* m3     = (float*)(ws + 62926848);
  float* out    = (float*)d_out;

  cast_x_k<<<8192, 256, 0, stream>>>(X, Xb);
  twcast_k<<<dim3(32, 32), 256, 0, stream>>>(Wq, Wqkvt + 0,       1024, 1024);
  twcast_k<<<dim3(32, 32), 256, 0, stream>>>(Wk, Wqkvt + 1048576, 1024, 1024);
  twcast_k<<<dim3(32, 32), 256, 0, stream>>>(Wv, Wqkvt + 2097152, 1024, 1024);
  twcast_k<<<dim3(32, 32), 256, 0, stream>>>(W1, W1t, 1024, 1024);
  twcast_k<<<dim3(32, 32), 256, 0, stream>>>(W2, W2t, 1024, 1024);
  twcast_k<<<dim3(32, 32), 256, 0, stream>>>(W3, W3t, 1024, 1024);
  cbias_k<<<12, 256, 0, stream>>>(bq, bk, bv, bqkv);

  // QKV: [8192,1024] x [3072,1024]^T -> bf16 [8192,3072]; grid 32x12=384
  gemm8p<<<384, 512, 0, stream>>>(
      Xb, Wqkvt, bqkv, 1.0f, qkv, 1024, 1024, 1024, 3072, 0, 0, 0, 1, 32, 12);

  tv_k<<<dim3(32, 64, 4), 256, 0, stream>>>(qkv, vT);

  // scores[b] = q k^T / 32 -> bf16 [2048,2048]; grid 8x8x4=256
  gemm8p<<<256, 512, 0, stream>>>(
      qkv, qkv + 1024, nullptr, 0.03125f, scores, 1024, 3072, 3072, 2048,
      (long)2048 * 3072, (long)2048 * 3072, (long)2048 * 2048, 0, 8, 8);

  softmax_k<<<8192, 256, 0, stream>>>(scores);

  // ctx[b] = attn @ v (fp32 out); grid 8x4x4=128
  gemm8p<<<128, 512, 0, stream>>>(
      scores, vT, nullptr, 1.0f, ctx, 2048, 2048, 2048, 1024,
      (long)2048 * 2048, (long)1024 * 2048, (long)2048 * 1024, 4, 8, 4);

  addln_k<<<8192, 256, 0, stream>>>(ctx, X, g1, be1, h, hb);

  // MLP; grid 32x4=128 each
  gemm8p<<<128, 512, 0, stream>>>(
      hb, W1t, b1, 1.0f, m1, 1024, 1024, 1024, 1024, 0, 0, 0, 3, 32, 4);
  gemm8p<<<128, 512, 0, stream>>>(
      m1, W2t, b2, 1.0f, m2, 1024, 1024, 1024, 1024, 0, 0, 0, 3, 32, 4);
  gemm8p<<<128, 512, 0, stream>>>(
      m2, W3t, b3, 1.0f, m3, 1024, 1024, 1024, 1024, 0, 0, 0, 5, 32, 4);

  addln_k<<<8192, 256, 0, stream>>>(m3, h, g2, be2, out, nullptr);
}

// Round 4
// 317.246 us; speedup vs baseline: 1.2445x; 1.1808x over previous
//
#include <hip/hip_runtime.h>
#include <hip/hip_bf16.h>

// TransformerBlock: N=4, T=2048, D=1024. bf16 MFMA 16x16x32, NT GEMMs.
// gemm256: 256x256 tile, 8 waves 2Mx4N, 4 phases/K-tile, 1 barrier/phase.
// gemm128: 256x128 tile, 8 waves 4Mx2N, same skeleton, 96KB LDS, for
//          full-grid shapes (ctx, MLP). XOR-swizzled LDS both. No XCD swizzle
//          (R3 showed it 2.5x's FETCH_SIZE on these grids).

typedef __attribute__((ext_vector_type(8))) short short8;
typedef __attribute__((ext_vector_type(4))) short short4v;
typedef __attribute__((ext_vector_type(4))) float float4v;

#define DEVI static __device__ __forceinline__

DEVI float bf2f(short s) {
  union { unsigned u; float f; } c;
  c.u = ((unsigned)(unsigned short)s) << 16;
  return c.f;
}
DEVI short f2bf(float f) {
  union { __hip_bfloat16 h; short s; } c;
  c.h = __float2bfloat16(f);
  return c.s;
}
DEVI void gload_lds16(const void* g, void* l) {
  __builtin_amdgcn_global_load_lds(
      (const __attribute__((address_space(1))) void*)g,
      (__attribute__((address_space(3))) void*)l, 16, 0, 0);
}

#define MFMA16 __builtin_amdgcn_mfma_f32_16x16x32_bf16
#define CFENCE asm volatile("" ::: "memory")

// ---------------- 256x256 GEMM (QKV, scores) ----------------
__global__ __launch_bounds__(512, 2) void gemm256(
    const short* __restrict__ A, const short* __restrict__ B,
    const float* __restrict__ bias, float alpha, void* __restrict__ Cout,
    int K, int lda, int ldb, int ldc,
    long sA, long sB, long sC, int flags)
{
  __shared__ __attribute__((aligned(16))) short lds[65536];

  const int tid  = threadIdx.x;
  const int lane = tid & 63;
  const int wid  = tid >> 6;
  const int wm = wid >> 2, wn = wid & 3;   // 2(M) x 4(N); wave owns 128x64
  const int lr = lane & 15;
  const int kq = lane >> 4;

  const long m0 = (long)blockIdx.x * 256;
  const long n0 = (long)blockIdx.y * 256;
  const short* Ab = A + (long)blockIdx.z * sA;
  const short* Bb = B + (long)blockIdx.z * sB;

  const int sc8 = (((tid & 7) ^ ((tid >> 3) & 7)) << 3);

  auto stageA = [&](int kt, int half) {
    char* buf = (char*)lds + (kt & 1) * 32768;
    const long k0 = (long)kt * 64 + sc8;
#pragma unroll
    for (int q = 0; q < 2; ++q) {
      const int row = half * 64 + q * 128 + (tid >> 3);
      gload_lds16(Ab + (m0 + row) * (long)lda + k0,
                  buf + half * 8192 + q * 16384 + tid * 16);
    }
  };
  auto stageB = [&](int kt, int half) {
    char* buf = (char*)lds + 65536 + (kt & 1) * 32768;
    const long k0 = (long)kt * 64 + sc8;
#pragma unroll
    for (int q = 0; q < 2; ++q) {
      const int row = half * 32 + (q * 2 + (tid >> 8)) * 64 + ((tid >> 3) & 31);
      gload_lds16(Bb + (n0 + row) * (long)ldb + k0,
                  buf + half * 4096 + q * 16384 + (tid >> 8) * 8192 + (tid & 255) * 16);
    }
  };

  auto rdA = [&](int kt, int fm, int kk) -> short8 {
    const char* buf = (const char*)lds + (kt & 1) * 32768;
    const int row = wm * 128 + fm * 16 + lr;
    const int off = row * 128 + ((((kk << 2) + kq) ^ (lr & 7)) << 4);
    return *(const short8*)(buf + off);
  };
  auto rdB = [&](int kt, int fn, int kk) -> short8 {
    const char* buf = (const char*)lds + 65536 + (kt & 1) * 32768;
    const int row = wn * 64 + fn * 16 + lr;
    const int off = row * 128 + ((((kk << 2) + kq) ^ (lr & 7)) << 4);
    return *(const short8*)(buf + off);
  };

  float4v acc[8][4];
#pragma unroll
  for (int m = 0; m < 8; ++m)
#pragma unroll
    for (int n = 0; n < 4; ++n)
#pragma unroll
      for (int i = 0; i < 4; ++i) acc[m][n][i] = 0.f;

  const int NT = K >> 6;

  stageA(0, 0); stageB(0, 0); stageB(0, 1); stageA(0, 1);
  stageA(1, 0); stageB(1, 0);
  asm volatile("s_waitcnt vmcnt(4)" ::: "memory");
  __builtin_amdgcn_s_barrier();
  CFENCE;

  short8 a0[4][2], a1[4][2], b0[2][2], b1[2][2];

  for (int t = 0; t < NT; ++t) {
    // P1: read A-low + B-low; stage uB1(t+1); MFMA Q00
#pragma unroll
    for (int m = 0; m < 4; ++m) { a0[m][0] = rdA(t, m, 0); a0[m][1] = rdA(t, m, 1); }
#pragma unroll
    for (int n = 0; n < 2; ++n) { b0[n][0] = rdB(t, n, 0); b0[n][1] = rdB(t, n, 1); }
    if (t + 1 < NT) stageB(t + 1, 1);
    __builtin_amdgcn_s_barrier();
    CFENCE;
    asm volatile("s_waitcnt lgkmcnt(0)" ::: "memory");
    __builtin_amdgcn_sched_barrier(0);
    __builtin_amdgcn_s_setprio(1);
#pragma unroll
    for (int m = 0; m < 4; ++m)
#pragma unroll
      for (int n = 0; n < 2; ++n)
#pragma unroll
        for (int kk = 0; kk < 2; ++kk)
          acc[m][n] = MFMA16(a0[m][kk], b0[n][kk], acc[m][n], 0, 0, 0);
    __builtin_amdgcn_s_setprio(0);

    // P2: read B-high; stage uA1(t+1); MFMA Q01
#pragma unroll
    for (int n = 0; n < 2; ++n) { b1[n][0] = rdB(t, n + 2, 0); b1[n][1] = rdB(t, n + 2, 1); }
    if (t + 1 < NT) stageA(t + 1, 1);
    __builtin_amdgcn_s_barrier();
    CFENCE;
    asm volatile("s_waitcnt lgkmcnt(0)" ::: "memory");
    __builtin_amdgcn_sched_barrier(0);
    __builtin_amdgcn_s_setprio(1);
#pragma unroll
    for (int m = 0; m < 4; ++m)
#pragma unroll
      for (int n = 0; n < 2; ++n)
#pragma unroll
        for (int kk = 0; kk < 2; ++kk)
          acc[m][n + 2] = MFMA16(a0[m][kk], b1[n][kk], acc[m][n + 2], 0, 0, 0);
    __builtin_amdgcn_s_setprio(0);

    // P3: read A-high; stage uA0(t+2); MFMA Q10
#pragma unroll
    for (int m = 0; m < 4; ++m) { a1[m][0] = rdA(t, m + 4, 0); a1[m][1] = rdA(t, m + 4, 1); }
    if (t + 2 < NT) stageA(t + 2, 0);
    __builtin_amdgcn_s_barrier();
    CFENCE;
    asm volatile("s_waitcnt lgkmcnt(0)" ::: "memory");
    __builtin_amdgcn_sched_barrier(0);
    __builtin_amdgcn_s_setprio(1);
#pragma unroll
    for (int m = 0; m < 4; ++m)
#pragma unroll
      for (int n = 0; n < 2; ++n)
#pragma unroll
        for (int kk = 0; kk < 2; ++kk)
          acc[m + 4][n] = MFMA16(a1[m][kk], b0[n][kk], acc[m + 4][n], 0, 0, 0);
    __builtin_amdgcn_s_setprio(0);

    // P4: stage uB0(t+2); vmcnt checkpoint; MFMA Q11
    if (t + 2 < NT) stageB(t + 2, 0);
    if (t + 2 < NT) { asm volatile("s_waitcnt vmcnt(4)" ::: "memory"); }
    else            { asm volatile("s_waitcnt vmcnt(0)" ::: "memory"); }
    __builtin_amdgcn_s_barrier();
    CFENCE;
    __builtin_amdgcn_sched_barrier(0);
    __builtin_amdgcn_s_setprio(1);
#pragma unroll
    for (int m = 0; m < 4; ++m)
#pragma unroll
      for (int n = 0; n < 2; ++n)
#pragma unroll
        for (int kk = 0; kk < 2; ++kk)
          acc[m + 4][n + 2] = MFMA16(a1[m][kk], b1[n][kk], acc[m + 4][n + 2], 0, 0, 0);
    __builtin_amdgcn_s_setprio(0);
  }

  const int dob = flags & 1, dor = flags & 2, f32o = flags & 4;
  float* Cf = (float*)Cout + (long)blockIdx.z * sC;
  short* Cb = (short*)Cout + (long)blockIdx.z * sC;
  const long r0 = m0 + wm * 128 + kq * 4;
  const long c0 = n0 + wn * 64 + lr;
#pragma unroll
  for (int m = 0; m < 8; ++m)
#pragma unroll
    for (int n = 0; n < 4; ++n) {
      const long c = c0 + n * 16;
      float bv = dob ? bias[c] : 0.f;
#pragma unroll
      for (int i = 0; i < 4; ++i) {
        const long r = r0 + m * 16 + i;
        float v = acc[m][n][i] * alpha + bv;
        if (dor) v = fmaxf(v, 0.f);
        if (f32o) Cf[r * ldc + c] = v;
        else      Cb[r * ldc + c] = f2bf(v);
      }
    }
}

// ---------------- 256x128 GEMM (ctx, MLP) ----------------
// waves 4(M) x 2(N), wave owns 64x64. LDS: A 2x32KB @0, B 2x16KB @65536 (96KB).
// Stage units: uAlow/uAhigh = A rows with (r&63)<32 / >=32 (16KB, 2 loads/thr);
// uBlow/uBhigh same for B (8KB, 1 load/thr). Ckpts: vmcnt(4)@P2, vmcnt(2)@P4.
__global__ __launch_bounds__(512, 2) void gemm128(
    const short* __restrict__ A, const short* __restrict__ B,
    const float* __restrict__ bias, float alpha, void* __restrict__ Cout,
    int K, int lda, int ldb, int ldc,
    long sA, long sB, long sC, int flags)
{
  __shared__ __attribute__((aligned(16))) short lds[49152];

  const int tid  = threadIdx.x;
  const int lane = tid & 63;
  const int wid  = tid >> 6;
  const int wm = wid >> 1, wn = wid & 1;   // 4(M) x 2(N)
  const int lr = lane & 15;
  const int kq = lane >> 4;

  const long m0 = (long)blockIdx.x * 256;
  const long n0 = (long)blockIdx.y * 128;
  const short* Ab = A + (long)blockIdx.z * sA;
  const short* Bb = B + (long)blockIdx.z * sB;

  const int sc8 = (((lane & 7) ^ (lane >> 3)) << 3);

  auto stA = [&](int kt, int half) {
    char* buf = (char*)lds + (kt & 1) * 32768;
    const long k0 = (long)kt * 64 + sc8;
#pragma unroll
    for (int q = 0; q < 2; ++q) {
      const int idx = q * 8 + wid;
      const int rowb = (idx >> 2) * 64 + half * 32 + (idx & 3) * 8;
      gload_lds16(Ab + (m0 + rowb + (lane >> 3)) * (long)lda + k0,
                  buf + rowb * 128 + lane * 16);
    }
  };
  auto stB = [&](int kt, int half) {
    char* buf = (char*)lds + 65536 + (kt & 1) * 16384;
    const long k0 = (long)kt * 64 + sc8;
    const int rowb = (wid >> 2) * 64 + half * 32 + (wid & 3) * 8;
    gload_lds16(Bb + (n0 + rowb + (lane >> 3)) * (long)ldb + k0,
                buf + rowb * 128 + lane * 16);
  };

  auto rdA = [&](int kt, int fm, int kk) -> short8 {
    const char* buf = (const char*)lds + (kt & 1) * 32768;
    const int row = wm * 64 + fm * 16 + lr;
    const int off = row * 128 + ((((kk << 2) + kq) ^ (lr & 7)) << 4);
    return *(const short8*)(buf + off);
  };
  auto rdB = [&](int kt, int fn, int kk) -> short8 {
    const char* buf = (const char*)lds + 65536 + (kt & 1) * 16384;
    const int row = wn * 64 + fn * 16 + lr;
    const int off = row * 128 + ((((kk << 2) + kq) ^ (lr & 7)) << 4);
    return *(const short8*)(buf + off);
  };

  float4v acc[4][4];
#pragma unroll
  for (int m = 0; m < 4; ++m)
#pragma unroll
    for (int n = 0; n < 4; ++n)
#pragma unroll
      for (int i = 0; i < 4; ++i) acc[m][n][i] = 0.f;

  const int NT = K >> 6;

  // prologue: tile0 fully staged; uAlow/uB must be complete (allow uAhigh in flight)
  stA(0, 0); stB(0, 0); stB(0, 1); stA(0, 1);
  asm volatile("s_waitcnt vmcnt(2)" ::: "memory");
  __builtin_amdgcn_s_barrier();
  CFENCE;

  short8 a0[2][2], a1[2][2], b0[2][2], b1[2][2];

  for (int t = 0; t < NT; ++t) {
    // P1: read a[0,1], b[0,1]; stage uAlow(t+1); MFMA m{0,1} n{0,1}
#pragma unroll
    for (int m = 0; m < 2; ++m) { a0[m][0] = rdA(t, m, 0); a0[m][1] = rdA(t, m, 1); }
#pragma unroll
    for (int n = 0; n < 2; ++n) { b0[n][0] = rdB(t, n, 0); b0[n][1] = rdB(t, n, 1); }
    if (t + 1 < NT) stA(t + 1, 0);
    __builtin_amdgcn_s_barrier();
    CFENCE;
    asm volatile("s_waitcnt lgkmcnt(0)" ::: "memory");
    __builtin_amdgcn_sched_barrier(0);
    __builtin_amdgcn_s_setprio(1);
#pragma unroll
    for (int m = 0; m < 2; ++m)
#pragma unroll
      for (int n = 0; n < 2; ++n)
#pragma unroll
        for (int kk = 0; kk < 2; ++kk)
          acc[m][n] = MFMA16(a0[m][kk], b0[n][kk], acc[m][n], 0, 0, 0);
    __builtin_amdgcn_s_setprio(0);

    // P2: read b[2,3]; stage uBlow+uBhigh(t+1); vmcnt(4); MFMA m{0,1} n{2,3}
#pragma unroll
    for (int n = 0; n < 2; ++n) { b1[n][0] = rdB(t, n + 2, 0); b1[n][1] = rdB(t, n + 2, 1); }
    if (t + 1 < NT) { stB(t + 1, 0); stB(t + 1, 1); }
    asm volatile("s_waitcnt vmcnt(4)" ::: "memory");
    __builtin_amdgcn_s_barrier();
    CFENCE;
    asm volatile("s_waitcnt lgkmcnt(0)" ::: "memory");
    __builtin_amdgcn_sched_barrier(0);
    __builtin_amdgcn_s_setprio(1);
#pragma unroll
    for (int m = 0; m < 2; ++m)
#pragma unroll
      for (int n = 0; n < 2; ++n)
#pragma unroll
        for (int kk = 0; kk < 2; ++kk)
          acc[m][n + 2] = MFMA16(a0[m][kk], b1[n][kk], acc[m][n + 2], 0, 0, 0);
    __builtin_amdgcn_s_setprio(0);

    // P3: read a[2,3]; stage uAhigh(t+1); MFMA m{2,3} n{0,1}
#pragma unroll
    for (int m = 0; m < 2; ++m) { a1[m][0] = rdA(t, m + 2, 0); a1[m][1] = rdA(t, m + 2, 1); }
    if (t + 1 < NT) stA(t + 1, 1);
    __builtin_amdgcn_s_barrier();
    CFENCE;
    asm volatile("s_waitcnt lgkmcnt(0)" ::: "memory");
    __builtin_amdgcn_sched_barrier(0);
    __builtin_amdgcn_s_setprio(1);
#pragma unroll
    for (int m = 0; m < 2; ++m)
#pragma unroll
      for (int n = 0; n < 2; ++n)
#pragma unroll
        for (int kk = 0; kk < 2; ++kk)
          acc[m + 2][n] = MFMA16(a1[m][kk], b0[n][kk], acc[m + 2][n], 0, 0, 0);
    __builtin_amdgcn_s_setprio(0);

    // P4: vmcnt(2); MFMA m{2,3} n{2,3}
    if (t + 1 < NT) { asm volatile("s_waitcnt vmcnt(2)" ::: "memory"); }
    else            { asm volatile("s_waitcnt vmcnt(0)" ::: "memory"); }
    __builtin_amdgcn_s_barrier();
    CFENCE;
    __builtin_amdgcn_sched_barrier(0);
    __builtin_amdgcn_s_setprio(1);
#pragma unroll
    for (int m = 0; m < 2; ++m)
#pragma unroll
      for (int n = 0; n < 2; ++n)
#pragma unroll
        for (int kk = 0; kk < 2; ++kk)
          acc[m + 2][n + 2] = MFMA16(a1[m][kk], b1[n][kk], acc[m + 2][n + 2], 0, 0, 0);
    __builtin_amdgcn_s_setprio(0);
  }

  const int dob = flags & 1, dor = flags & 2, f32o = flags & 4;
  float* Cf = (float*)Cout + (long)blockIdx.z * sC;
  short* Cb = (short*)Cout + (long)blockIdx.z * sC;
  const long r0 = m0 + wm * 64 + kq * 4;
  const long c0 = n0 + wn * 64 + lr;
#pragma unroll
  for (int m = 0; m < 4; ++m)
#pragma unroll
    for (int n = 0; n < 4; ++n) {
      const long c = c0 + n * 16;
      float bv = dob ? bias[c] : 0.f;
#pragma unroll
      for (int i = 0; i < 4; ++i) {
        const long r = r0 + m * 16 + i;
        float v = acc[m][n][i] * alpha + bv;
        if (dor) v = fmaxf(v, 0.f);
        if (f32o) Cf[r * ldc + c] = v;
        else      Cb[r * ldc + c] = f2bf(v);
      }
    }
}

// ---------------- elementwise / utility kernels ----------------

__global__ __launch_bounds__(256) void cast_x_k(const float* __restrict__ X,
                                                short* __restrict__ Xb) {
  int i = blockIdx.x * 256 + threadIdx.x;
  float4v v = ((const float4v*)X)[i];
  short4v o;
#pragma unroll
  for (int j = 0; j < 4; ++j) o[j] = f2bf(v[j]);
  ((short4v*)Xb)[i] = o;
}

__global__ __launch_bounds__(256) void twcast_k(const float* __restrict__ W,
                                                short* __restrict__ Wt,
                                                int rows, int cols) {
  __shared__ float tile[32][33];
  int tx = threadIdx.x & 31, ty = threadIdx.x >> 5;
  int c0 = blockIdx.x * 32, r0 = blockIdx.y * 32;
#pragma unroll
  for (int r = ty; r < 32; r += 8)
    tile[r][tx] = W[(long)(r0 + r) * cols + c0 + tx];
  __syncthreads();
#pragma unroll
  for (int r = ty; r < 32; r += 8)
    Wt[(long)(c0 + r) * rows + r0 + tx] = f2bf(tile[tx][r]);
}

__global__ void cbias_k(const float* __restrict__ bq, const float* __restrict__ bk,
                        const float* __restrict__ bv, float* __restrict__ o) {
  int i = blockIdx.x * 256 + threadIdx.x;
  if (i < 1024) o[i] = bq[i];
  else if (i < 2048) o[i] = bk[i - 1024];
  else if (i < 3072) o[i] = bv[i - 2048];
}

__global__ __launch_bounds__(256) void tv_k(const short* __restrict__ qkv,
                                            short* __restrict__ vT) {
  __shared__ short tile[32][33];
  int b = blockIdx.z;
  int tx = threadIdx.x & 31, ty = threadIdx.x >> 5;
  int d0 = blockIdx.x * 32, t0 = blockIdx.y * 32;
#pragma unroll
  for (int r = ty; r < 32; r += 8)
    tile[r][tx] = qkv[((long)(b * 2048 + t0 + r)) * 3072 + 2048 + d0 + tx];
  __syncthreads();
#pragma unroll
  for (int r = ty; r < 32; r += 8)
    vT[(long)b * 2097152 + (long)(d0 + r) * 2048 + t0 + tx] = tile[tx][r];
}

__global__ __launch_bounds__(256) void softmax_k(short* __restrict__ s) {
  __shared__ float red[8];
  long r = blockIdx.x;
  short* p = s + r * 2048;
  int tid = threadIdx.x;
  short8 raw = *(short8*)&p[tid * 8];
  float v[8];
  float mx = -1e30f;
#pragma unroll
  for (int j = 0; j < 8; ++j) { v[j] = bf2f(raw[j]); mx = fmaxf(mx, v[j]); }
#pragma unroll
  for (int o = 32; o; o >>= 1) mx = fmaxf(mx, __shfl_xor(mx, o));
  if ((tid & 63) == 0) red[tid >> 6] = mx;
  __syncthreads();
  mx = fmaxf(fmaxf(red[0], red[1]), fmaxf(red[2], red[3]));
  float sum = 0.f;
#pragma unroll
  for (int j = 0; j < 8; ++j) { v[j] = __expf(v[j] - mx); sum += v[j]; }
#pragma unroll
  for (int o = 32; o; o >>= 1) sum += __shfl_xor(sum, o);
  if ((tid & 63) == 0) red[4 + (tid >> 6)] = sum;
  __syncthreads();
  float inv = 1.f / (red[4] + red[5] + red[6] + red[7]);
  short8 o8;
#pragma unroll
  for (int j = 0; j < 8; ++j) o8[j] = f2bf(v[j] * inv);
  *(short8*)&p[tid * 8] = o8;
}

__global__ __launch_bounds__(256) void addln_k(const float* __restrict__ a,
                                               const float* __restrict__ b,
                                               const float* __restrict__ g,
                                               const float* __restrict__ be,
                                               float* __restrict__ outf,
                                               short* __restrict__ outb) {
  __shared__ float red[8];
  long r = blockIdx.x;
  int tid = threadIdx.x;
  float4v va = ((const float4v*)(a + r * 1024))[tid];
  float4v vb = ((const float4v*)(b + r * 1024))[tid];
  float x[4]; float s = 0.f;
#pragma unroll
  for (int j = 0; j < 4; ++j) { x[j] = va[j] + vb[j]; s += x[j]; }
#pragma unroll
  for (int o = 32; o; o >>= 1) s += __shfl_xor(s, o);
  if ((tid & 63) == 0) red[tid >> 6] = s;
  __syncthreads();
  float mu = (red[0] + red[1] + red[2] + red[3]) * (1.f / 1024.f);
  float ss = 0.f;
#pragma unroll
  for (int j = 0; j < 4; ++j) { float d = x[j] - mu; ss += d * d; }
#pragma unroll
  for (int o = 32; o; o >>= 1) ss += __shfl_xor(ss, o);
  if ((tid & 63) == 0) red[4 + (tid >> 6)] = ss;
  __syncthreads();
  float var = (red[4] + red[5] + red[6] + red[7]) * (1.f / 1024.f);
  float rstd = rsqrtf(var + 1e-5f);
  float4v vg = ((const float4v*)g)[tid];
  float4v vbe = ((const float4v*)be)[tid];
  float4v y;
#pragma unroll
  for (int j = 0; j < 4; ++j) y[j] = (x[j] - mu) * rstd * vg[j] + vbe[j];
  ((float4v*)(outf + r * 1024))[tid] = y;
  if (outb) {
    short4v ob;
#pragma unroll
    for (int j = 0; j < 4; ++j) ob[j] = f2bf(y[j]);
    ((short4v*)(outb + r * 1024))[tid] = ob;
  }
}

// ---------------- host launcher ----------------

extern "C" void kernel_launch(void* const* d_in, const int* in_sizes, int n_in,
                              void* d_out, int out_size, void* d_ws, size_t ws_size,
                              hipStream_t stream) {
  const float* X  = (const float*)d_in[0];
  const float* Wq = (const float*)d_in[1];
  const float* bq = (const float*)d_in[2];
  const float* Wk = (const float*)d_in[3];
  const float* bk = (const float*)d_in[4];
  const float* Wv = (const float*)d_in[5];
  const float* bv = (const float*)d_in[6];
  const float* W1 = (const float*)d_in[7];
  const float* b1 = (const float*)d_in[8];
  const float* W2 = (const float*)d_in[9];
  const float* b2 = (const float*)d_in[10];
  const float* W3 = (const float*)d_in[11];
  const float* b3 = (const float*)d_in[12];
  const float* g1  = (const float*)d_in[13];
  const float* be1 = (const float*)d_in[14];
  const float* g2  = (const float*)d_in[15];
  const float* be2 = (const float*)d_in[16];

  char* ws = (char*)d_ws;
  short* Xb     = (short*)(ws + 0);
  short* Wqkvt  = (short*)(ws + 16777216);
  short* W1t    = (short*)(ws + 23068672);
  short* W2t    = (short*)(ws + 25165824);
  short* W3t    = (short*)(ws + 27262976);
  float* bqkv   = (float*)(ws + 29360128);
  short* qkv    = (short*)(ws + 29372416);
  short* vT     = (short*)(ws + 79704064);
  short* scores = (short*)(ws + 96481280);
  float* ctx    = (float*)(ws + 29372416);
  float* h      = (float*)(ws + 96481280);
  short* hb     = (short*)(ws + 0);
  short* m1     = (short*)(ws + 29372416);
  short* m2     = (short*)(ws + 46149632);
  float* m3     = (float*)(ws + 62926848);
  float* out    = (float*)d_out;

  cast_x_k<<<8192, 256, 0, stream>>>(X, Xb);
  twcast_k<<<dim3(32, 32), 256, 0, stream>>>(Wq, Wqkvt + 0,       1024, 1024);
  twcast_k<<<dim3(32, 32), 256, 0, stream>>>(Wk, Wqkvt + 1048576, 1024, 1024);
  twcast_k<<<dim3(32, 32), 256, 0, stream>>>(Wv, Wqkvt + 2097152, 1024, 1024);
  twcast_k<<<dim3(32, 32), 256, 0, stream>>>(W1, W1t, 1024, 1024);
  twcast_k<<<dim3(32, 32), 256, 0, stream>>>(W2, W2t, 1024, 1024);
  twcast_k<<<dim3(32, 32), 256, 0, stream>>>(W3, W3t, 1024, 1024);
  cbias_k<<<12, 256, 0, stream>>>(bq, bk, bv, bqkv);

  // QKV: [8192,1024] x [3072,1024]^T -> bf16 [8192,3072]
  gemm256<<<dim3(32, 12, 1), 512, 0, stream>>>(
      Xb, Wqkvt, bqkv, 1.0f, qkv, 1024, 1024, 1024, 3072, 0, 0, 0, 1);

  tv_k<<<dim3(32, 64, 4), 256, 0, stream>>>(qkv, vT);

  // scores[b] = q k^T / 32 -> bf16 [2048,2048]; 256 blocks = 1 full round
  gemm256<<<dim3(8, 8, 4), 512, 0, stream>>>(
      qkv, qkv + 1024, nullptr, 0.03125f, scores, 1024, 3072, 3072, 2048,
      (long)2048 * 3072, (long)2048 * 3072, (long)2048 * 2048, 0);

  softmax_k<<<8192, 256, 0, stream>>>(scores);

  // ctx[b] = attn @ v (fp32 out); 256x128 tiles -> 256 blocks
  gemm128<<<dim3(8, 8, 4), 512, 0, stream>>>(
      scores, vT, nullptr, 1.0f, ctx, 2048, 2048, 2048, 1024,
      (long)2048 * 2048, (long)1024 * 2048, (long)2048 * 1024, 4);

  addln_k<<<8192, 256, 0, stream>>>(ctx, X, g1, be1, h, hb);

  // MLP: 256x128 tiles -> 256 blocks each
  gemm128<<<dim3(32, 8, 1), 512, 0, stream>>>(
      hb, W1t, b1, 1.0f, m1, 1024, 1024, 1024, 1024, 0, 0, 0, 3);
  gemm128<<<dim3(32, 8, 1), 512, 0, stream>>>(
      m1, W2t, b2, 1.0f, m2, 1024, 1024, 1024, 1024, 0, 0, 0, 3);
  gemm128<<<dim3(32, 8, 1), 512, 0, stream>>>(
      m2, W3t, b3, 1.0f, m3, 1024, 1024, 1024, 1024, 0, 0, 0, 5);

  addln_k<<<8192, 256, 0, stream>>>(m3, h, g2, be2, out, nullptr);
}

// Round 5
// 311.377 us; speedup vs baseline: 1.2679x; 1.0188x over previous
//
#include <hip/hip_runtime.h>
#include <hip/hip_bf16.h>

// TransformerBlock: N=4, T=2048, D=1024. bf16 MFMA 16x16x32, NT GEMMs.
// R5: both GEMMs restructured to 2 barriers/K-tile with ds_reads issued at the
// tail of the previous phase (overlapping the MFMA pipe window). Counted vmcnt
// checkpoints re-derived; XOR-swizzled LDS; setprio around MFMA clusters.

typedef __attribute__((ext_vector_type(8))) short short8;
typedef __attribute__((ext_vector_type(4))) short short4v;
typedef __attribute__((ext_vector_type(4))) float float4v;

#define DEVI static __device__ __forceinline__

DEVI float bf2f(short s) {
  union { unsigned u; float f; } c;
  c.u = ((unsigned)(unsigned short)s) << 16;
  return c.f;
}
DEVI short f2bf(float f) {
  union { __hip_bfloat16 h; short s; } c;
  c.h = __float2bfloat16(f);
  return c.s;
}
DEVI void gload_lds16(const void* g, void* l) {
  __builtin_amdgcn_global_load_lds(
      (const __attribute__((address_space(1))) void*)g,
      (__attribute__((address_space(3))) void*)l, 16, 0, 0);
}

#define MFMA16 __builtin_amdgcn_mfma_f32_16x16x32_bf16
#define CFENCE asm volatile("" ::: "memory")
#define SCHEDB __builtin_amdgcn_sched_barrier(0)

// ---------------- 256x256 GEMM (QKV, scores): 2 phases/K-tile ----------------
// flags: 1=bias, 2=relu, 4=fp32 output (else bf16)
__global__ __launch_bounds__(512, 2) void gemm256(
    const short* __restrict__ A, const short* __restrict__ B,
    const float* __restrict__ bias, float alpha, void* __restrict__ Cout,
    int K, int lda, int ldb, int ldc,
    long sA, long sB, long sC, int flags)
{
  __shared__ __attribute__((aligned(16))) short lds[65536];

  const int tid  = threadIdx.x;
  const int lane = tid & 63;
  const int wid  = tid >> 6;
  const int wm = wid >> 2, wn = wid & 3;   // 2(M) x 4(N); wave owns 128x64
  const int lr = lane & 15;
  const int kq = lane >> 4;

  const long m0 = (long)blockIdx.x * 256;
  const long n0 = (long)blockIdx.y * 256;
  const short* Ab = A + (long)blockIdx.z * sA;
  const short* Bb = B + (long)blockIdx.z * sB;

  const int sc8 = (((tid & 7) ^ ((tid >> 3) & 7)) << 3);

  auto stageA = [&](int kt, int half) {   // 2 loads/thread; uA0: rows 0-63,128-191; uA1: 64-127,192-255
    char* buf = (char*)lds + (kt & 1) * 32768;
    const long k0 = (long)kt * 64 + sc8;
#pragma unroll
    for (int q = 0; q < 2; ++q) {
      const int row = half * 64 + q * 128 + (tid >> 3);
      gload_lds16(Ab + (m0 + row) * (long)lda + k0,
                  buf + half * 8192 + q * 16384 + tid * 16);
    }
  };
  auto stageB = [&](int kt, int half) {   // 2 loads/thread
    char* buf = (char*)lds + 65536 + (kt & 1) * 32768;
    const long k0 = (long)kt * 64 + sc8;
#pragma unroll
    for (int q = 0; q < 2; ++q) {
      const int row = half * 32 + (q * 2 + (tid >> 8)) * 64 + ((tid >> 3) & 31);
      gload_lds16(Bb + (n0 + row) * (long)ldb + k0,
                  buf + half * 4096 + q * 16384 + (tid >> 8) * 8192 + (tid & 255) * 16);
    }
  };

  auto rdA = [&](int kt, int fm, int kk) -> short8 {
    const char* buf = (const char*)lds + (kt & 1) * 32768;
    const int row = wm * 128 + fm * 16 + lr;
    const int off = row * 128 + ((((kk << 2) + kq) ^ (lr & 7)) << 4);
    return *(const short8*)(buf + off);
  };
  auto rdB = [&](int kt, int fn, int kk) -> short8 {
    const char* buf = (const char*)lds + 65536 + (kt & 1) * 32768;
    const int row = wn * 64 + fn * 16 + lr;
    const int off = row * 128 + ((((kk << 2) + kq) ^ (lr & 7)) << 4);
    return *(const short8*)(buf + off);
  };

  float4v acc[8][4];
#pragma unroll
  for (int m = 0; m < 8; ++m)
#pragma unroll
    for (int n = 0; n < 4; ++n)
#pragma unroll
      for (int i = 0; i < 4; ++i) acc[m][n][i] = 0.f;

  const int NT = K >> 6;

  // prologue: tile0 (4 units) + uA0/uB0 of tile1; vmcnt(4) -> tile0 complete
  stageA(0, 0); stageB(0, 0); stageB(0, 1); stageA(0, 1);
  stageA(1, 0); stageB(1, 0);
  asm volatile("s_waitcnt vmcnt(4)" ::: "memory");
  __builtin_amdgcn_s_barrier();
  CFENCE;

  short8 a0[4][2], a1[4][2], b0[2][2], b1[2][2];
  // pre-reads for PhA(0): a0, b0, b1 of tile 0
#pragma unroll
  for (int m = 0; m < 4; ++m) { a0[m][0] = rdA(0, m, 0); a0[m][1] = rdA(0, m, 1); }
#pragma unroll
  for (int n = 0; n < 2; ++n) {
    b0[n][0] = rdB(0, n, 0);     b0[n][1] = rdB(0, n, 1);
    b1[n][0] = rdB(0, n + 2, 0); b1[n][1] = rdB(0, n + 2, 1);
  }

  for (int t = 0; t < NT; ++t) {
    // ---- PhA: stage uB1/uA1(t+1); MFMA Q00+Q01; then issue a1(t) reads
    if (t + 1 < NT) { stageB(t + 1, 1); stageA(t + 1, 1); }
    __builtin_amdgcn_s_barrier();
    CFENCE;
    asm volatile("s_waitcnt lgkmcnt(0)" ::: "memory");
    SCHEDB;
    __builtin_amdgcn_s_setprio(1);
#pragma unroll
    for (int m = 0; m < 4; ++m)
#pragma unroll
      for (int n = 0; n < 2; ++n)
#pragma unroll
        for (int kk = 0; kk < 2; ++kk) {
          acc[m][n]     = MFMA16(a0[m][kk], b0[n][kk], acc[m][n], 0, 0, 0);
          acc[m][n + 2] = MFMA16(a0[m][kk], b1[n][kk], acc[m][n + 2], 0, 0, 0);
        }
    __builtin_amdgcn_s_setprio(0);
    SCHEDB;
#pragma unroll
    for (int m = 0; m < 4; ++m) { a1[m][0] = rdA(t, m + 4, 0); a1[m][1] = rdA(t, m + 4, 1); }

    // ---- PhB: stage uA0/uB0(t+2); ckpt; MFMA Q10+Q11; then issue reads(t+1)
    if (t + 2 < NT) { stageA(t + 2, 0); stageB(t + 2, 0); }
    if (t + 2 < NT) { asm volatile("s_waitcnt vmcnt(4)" ::: "memory"); }
    else            { asm volatile("s_waitcnt vmcnt(0)" ::: "memory"); }
    __builtin_amdgcn_s_barrier();
    CFENCE;
    asm volatile("s_waitcnt lgkmcnt(0)" ::: "memory");
    SCHEDB;
    __builtin_amdgcn_s_setprio(1);
#pragma unroll
    for (int m = 0; m < 4; ++m)
#pragma unroll
      for (int n = 0; n < 2; ++n)
#pragma unroll
        for (int kk = 0; kk < 2; ++kk) {
          acc[m + 4][n]     = MFMA16(a1[m][kk], b0[n][kk], acc[m + 4][n], 0, 0, 0);
          acc[m + 4][n + 2] = MFMA16(a1[m][kk], b1[n][kk], acc[m + 4][n + 2], 0, 0, 0);
        }
    __builtin_amdgcn_s_setprio(0);
    SCHEDB;
    if (t + 1 < NT) {
#pragma unroll
      for (int m = 0; m < 4; ++m) { a0[m][0] = rdA(t + 1, m, 0); a0[m][1] = rdA(t + 1, m, 1); }
#pragma unroll
      for (int n = 0; n < 2; ++n) {
        b0[n][0] = rdB(t + 1, n, 0);     b0[n][1] = rdB(t + 1, n, 1);
        b1[n][0] = rdB(t + 1, n + 2, 0); b1[n][1] = rdB(t + 1, n + 2, 1);
      }
    }
  }

  const int dob = flags & 1, dor = flags & 2, f32o = flags & 4;
  float* Cf = (float*)Cout + (long)blockIdx.z * sC;
  short* Cb = (short*)Cout + (long)blockIdx.z * sC;
  const long r0 = m0 + wm * 128 + kq * 4;
  const long c0 = n0 + wn * 64 + lr;
#pragma unroll
  for (int m = 0; m < 8; ++m)
#pragma unroll
    for (int n = 0; n < 4; ++n) {
      const long c = c0 + n * 16;
      float bv = dob ? bias[c] : 0.f;
#pragma unroll
      for (int i = 0; i < 4; ++i) {
        const long r = r0 + m * 16 + i;
        float v = acc[m][n][i] * alpha + bv;
        if (dor) v = fmaxf(v, 0.f);
        if (f32o) Cf[r * ldc + c] = v;
        else      Cb[r * ldc + c] = f2bf(v);
      }
    }
}

// ---------------- 256x128 GEMM (ctx, MLP): 2 phases/K-tile ----------------
__global__ __launch_bounds__(512, 2) void gemm128(
    const short* __restrict__ A, const short* __restrict__ B,
    const float* __restrict__ bias, float alpha, void* __restrict__ Cout,
    int K, int lda, int ldb, int ldc,
    long sA, long sB, long sC, int flags)
{
  __shared__ __attribute__((aligned(16))) short lds[49152];

  const int tid  = threadIdx.x;
  const int lane = tid & 63;
  const int wid  = tid >> 6;
  const int wm = wid >> 1, wn = wid & 1;   // 4(M) x 2(N); wave owns 64x64
  const int lr = lane & 15;
  const int kq = lane >> 4;

  const long m0 = (long)blockIdx.x * 256;
  const long n0 = (long)blockIdx.y * 128;
  const short* Ab = A + (long)blockIdx.z * sA;
  const short* Bb = B + (long)blockIdx.z * sB;

  const int sc8 = (((lane & 7) ^ (lane >> 3)) << 3);

  auto stA = [&](int kt, int half) {   // 2 loads/thread
    char* buf = (char*)lds + (kt & 1) * 32768;
    const long k0 = (long)kt * 64 + sc8;
#pragma unroll
    for (int q = 0; q < 2; ++q) {
      const int idx = q * 8 + wid;
      const int rowb = (idx >> 2) * 64 + half * 32 + (idx & 3) * 8;
      gload_lds16(Ab + (m0 + rowb + (lane >> 3)) * (long)lda + k0,
                  buf + rowb * 128 + lane * 16);
    }
  };
  auto stB = [&](int kt, int half) {   // 1 load/thread
    char* buf = (char*)lds + 65536 + (kt & 1) * 16384;
    const long k0 = (long)kt * 64 + sc8;
    const int rowb = (wid >> 2) * 64 + half * 32 + (wid & 3) * 8;
    gload_lds16(Bb + (n0 + rowb + (lane >> 3)) * (long)ldb + k0,
                buf + rowb * 128 + lane * 16);
  };

  auto rdA = [&](int kt, int fm, int kk) -> short8 {
    const char* buf = (const char*)lds + (kt & 1) * 32768;
    const int row = wm * 64 + fm * 16 + lr;
    const int off = row * 128 + ((((kk << 2) + kq) ^ (lr & 7)) << 4);
    return *(const short8*)(buf + off);
  };
  auto rdB = [&](int kt, int fn, int kk) -> short8 {
    const char* buf = (const char*)lds + 65536 + (kt & 1) * 16384;
    const int row = wn * 64 + fn * 16 + lr;
    const int off = row * 128 + ((((kk << 2) + kq) ^ (lr & 7)) << 4);
    return *(const short8*)(buf + off);
  };

  float4v acc[4][4];
#pragma unroll
  for (int m = 0; m < 4; ++m)
#pragma unroll
    for (int n = 0; n < 4; ++n)
#pragma unroll
      for (int i = 0; i < 4; ++i) acc[m][n][i] = 0.f;

  const int NT = K >> 6;

  // prologue: tile0 units (uAlow,uBlow,uBhigh,uAhigh); vmcnt(2) -> first 3 done
  stA(0, 0); stB(0, 0); stB(0, 1); stA(0, 1);
  asm volatile("s_waitcnt vmcnt(2)" ::: "memory");
  __builtin_amdgcn_s_barrier();
  CFENCE;

  short8 a0[2][2], a1[2][2], b0[2][2], b1[2][2];
#pragma unroll
  for (int m = 0; m < 2; ++m) { a0[m][0] = rdA(0, m, 0); a0[m][1] = rdA(0, m, 1); }
#pragma unroll
  for (int n = 0; n < 2; ++n) {
    b0[n][0] = rdB(0, n, 0);     b0[n][1] = rdB(0, n, 1);
    b1[n][0] = rdB(0, n + 2, 0); b1[n][1] = rdB(0, n + 2, 1);
  }

  for (int t = 0; t < NT; ++t) {
    // ---- PhA: stage uAlow/uBlow/uBhigh(t+1); ckpt vmcnt(4) [covers uAhigh(t)];
    //          MFMA m{0,1} x n{0..3}; then issue a1(t) reads
    if (t + 1 < NT) { stA(t + 1, 0); stB(t + 1, 0); stB(t + 1, 1); }
    if (t + 1 < NT) { asm volatile("s_waitcnt vmcnt(4)" ::: "memory"); }
    else            { asm volatile("s_waitcnt vmcnt(0)" ::: "memory"); }
    __builtin_amdgcn_s_barrier();
    CFENCE;
    asm volatile("s_waitcnt lgkmcnt(0)" ::: "memory");
    SCHEDB;
    __builtin_amdgcn_s_setprio(1);
#pragma unroll
    for (int m = 0; m < 2; ++m)
#pragma unroll
      for (int n = 0; n < 2; ++n)
#pragma unroll
        for (int kk = 0; kk < 2; ++kk) {
          acc[m][n]     = MFMA16(a0[m][kk], b0[n][kk], acc[m][n], 0, 0, 0);
          acc[m][n + 2] = MFMA16(a0[m][kk], b1[n][kk], acc[m][n + 2], 0, 0, 0);
        }
    __builtin_amdgcn_s_setprio(0);
    SCHEDB;
#pragma unroll
    for (int m = 0; m < 2; ++m) { a1[m][0] = rdA(t, m + 2, 0); a1[m][1] = rdA(t, m + 2, 1); }

    // ---- PhB: stage uAhigh(t+1); ckpt vmcnt(2) [covers uAlow/uB*(t+1)];
    //          MFMA m{2,3} x n{0..3}; then issue reads(t+1)
    if (t + 1 < NT) { stA(t + 1, 1); }
    if (t + 1 < NT) { asm volatile("s_waitcnt vmcnt(2)" ::: "memory"); }
    else            { asm volatile("s_waitcnt vmcnt(0)" ::: "memory"); }
    __builtin_amdgcn_s_barrier();
    CFENCE;
    asm volatile("s_waitcnt lgkmcnt(0)" ::: "memory");
    SCHEDB;
    __builtin_amdgcn_s_setprio(1);
#pragma unroll
    for (int m = 0; m < 2; ++m)
#pragma unroll
      for (int n = 0; n < 2; ++n)
#pragma unroll
        for (int kk = 0; kk < 2; ++kk) {
          acc[m + 2][n]     = MFMA16(a1[m][kk], b0[n][kk], acc[m + 2][n], 0, 0, 0);
          acc[m + 2][n + 2] = MFMA16(a1[m][kk], b1[n][kk], acc[m + 2][n + 2], 0, 0, 0);
        }
    __builtin_amdgcn_s_setprio(0);
    SCHEDB;
    if (t + 1 < NT) {
#pragma unroll
      for (int m = 0; m < 2; ++m) { a0[m][0] = rdA(t + 1, m, 0); a0[m][1] = rdA(t + 1, m, 1); }
#pragma unroll
      for (int n = 0; n < 2; ++n) {
        b0[n][0] = rdB(t + 1, n, 0);     b0[n][1] = rdB(t + 1, n, 1);
        b1[n][0] = rdB(t + 1, n + 2, 0); b1[n][1] = rdB(t + 1, n + 2, 1);
      }
    }
  }

  const int dob = flags & 1, dor = flags & 2, f32o = flags & 4;
  float* Cf = (float*)Cout + (long)blockIdx.z * sC;
  short* Cb = (short*)Cout + (long)blockIdx.z * sC;
  const long r0 = m0 + wm * 64 + kq * 4;
  const long c0 = n0 + wn * 64 + lr;
#pragma unroll
  for (int m = 0; m < 4; ++m)
#pragma unroll
    for (int n = 0; n < 4; ++n) {
      const long c = c0 + n * 16;
      float bv = dob ? bias[c] : 0.f;
#pragma unroll
      for (int i = 0; i < 4; ++i) {
        const long r = r0 + m * 16 + i;
        float v = acc[m][n][i] * alpha + bv;
        if (dor) v = fmaxf(v, 0.f);
        if (f32o) Cf[r * ldc + c] = v;
        else      Cb[r * ldc + c] = f2bf(v);
      }
    }
}

// ---------------- elementwise / utility kernels ----------------

__global__ __launch_bounds__(256) void cast_x_k(const float* __restrict__ X,
                                                short* __restrict__ Xb) {
  int i = blockIdx.x * 256 + threadIdx.x;
  float4v v = ((const float4v*)X)[i];
  short4v o;
#pragma unroll
  for (int j = 0; j < 4; ++j) o[j] = f2bf(v[j]);
  ((short4v*)Xb)[i] = o;
}

// all 6 weight transposes + bias concat in one launch; grid (32,32,7)
__global__ __launch_bounds__(256) void wcast_k(
    const float* __restrict__ Wq, const float* __restrict__ Wk,
    const float* __restrict__ Wv, const float* __restrict__ W1,
    const float* __restrict__ W2, const float* __restrict__ W3,
    const float* __restrict__ bq, const float* __restrict__ bk,
    const float* __restrict__ bv,
    short* __restrict__ Wqkvt, short* __restrict__ W1t,
    short* __restrict__ W2t, short* __restrict__ W3t,
    float* __restrict__ bqkv) {
  const int z = blockIdx.z;
  if (z == 6) {
    if (blockIdx.y != 0 || blockIdx.x >= 12) return;
    int i = blockIdx.x * 256 + threadIdx.x;
    bqkv[i] = i < 1024 ? bq[i] : (i < 2048 ? bk[i - 1024] : bv[i - 2048]);
    return;
  }
  const float* W = z == 0 ? Wq : z == 1 ? Wk : z == 2 ? Wv : z == 3 ? W1 : z == 4 ? W2 : W3;
  short* Wt = z == 0 ? Wqkvt : z == 1 ? Wqkvt + 1048576 : z == 2 ? Wqkvt + 2097152
            : z == 3 ? W1t : z == 4 ? W2t : W3t;
  __shared__ float tile[32][33];
  int tx = threadIdx.x & 31, ty = threadIdx.x >> 5;
  int c0 = blockIdx.x * 32, r0 = blockIdx.y * 32;
#pragma unroll
  for (int r = ty; r < 32; r += 8)
    tile[r][tx] = W[(long)(r0 + r) * 1024 + c0 + tx];
  __syncthreads();
#pragma unroll
  for (int r = ty; r < 32; r += 8)
    Wt[(long)(c0 + r) * 1024 + r0 + tx] = f2bf(tile[tx][r]);
}

__global__ __launch_bounds__(256) void tv_k(const short* __restrict__ qkv,
                                            short* __restrict__ vT) {
  __shared__ short tile[32][33];
  int b = blockIdx.z;
  int tx = threadIdx.x & 31, ty = threadIdx.x >> 5;
  int d0 = blockIdx.x * 32, t0 = blockIdx.y * 32;
#pragma unroll
  for (int r = ty; r < 32; r += 8)
    tile[r][tx] = qkv[((long)(b * 2048 + t0 + r)) * 3072 + 2048 + d0 + tx];
  __syncthreads();
#pragma unroll
  for (int r = ty; r < 32; r += 8)
    vT[(long)b * 2097152 + (long)(d0 + r) * 2048 + t0 + tx] = tile[tx][r];
}

__global__ __launch_bounds__(256) void softmax_k(short* __restrict__ s) {
  __shared__ float red[8];
  long r = blockIdx.x;
  short* p = s + r * 2048;
  int tid = threadIdx.x;
  short8 raw = *(short8*)&p[tid * 8];
  float v[8];
  float mx = -1e30f;
#pragma unroll
  for (int j = 0; j < 8; ++j) { v[j] = bf2f(raw[j]); mx = fmaxf(mx, v[j]); }
#pragma unroll
  for (int o = 32; o; o >>= 1) mx = fmaxf(mx, __shfl_xor(mx, o));
  if ((tid & 63) == 0) red[tid >> 6] = mx;
  __syncthreads();
  mx = fmaxf(fmaxf(red[0], red[1]), fmaxf(red[2], red[3]));
  float sum = 0.f;
#pragma unroll
  for (int j = 0; j < 8; ++j) { v[j] = __expf(v[j] - mx); sum += v[j]; }
#pragma unroll
  for (int o = 32; o; o >>= 1) sum += __shfl_xor(sum, o);
  if ((tid & 63) == 0) red[4 + (tid >> 6)] = sum;
  __syncthreads();
  float inv = 1.f / (red[4] + red[5] + red[6] + red[7]);
  short8 o8;
#pragma unroll
  for (int j = 0; j < 8; ++j) o8[j] = f2bf(v[j] * inv);
  *(short8*)&p[tid * 8] = o8;
}

__global__ __launch_bounds__(256) void addln_k(const float* __restrict__ a,
                                               const float* __restrict__ b,
                                               const float* __restrict__ g,
                                               const float* __restrict__ be,
                                               float* __restrict__ outf,
                                               short* __restrict__ outb) {
  __shared__ float red[8];
  long r = blockIdx.x;
  int tid = threadIdx.x;
  float4v va = ((const float4v*)(a + r * 1024))[tid];
  float4v vb = ((const float4v*)(b + r * 1024))[tid];
  float x[4]; float s = 0.f;
#pragma unroll
  for (int j = 0; j < 4; ++j) { x[j] = va[j] + vb[j]; s += x[j]; }
#pragma unroll
  for (int o = 32; o; o >>= 1) s += __shfl_xor(s, o);
  if ((tid & 63) == 0) red[tid >> 6] = s;
  __syncthreads();
  float mu = (red[0] + red[1] + red[2] + red[3]) * (1.f / 1024.f);
  float ss = 0.f;
#pragma unroll
  for (int j = 0; j < 4; ++j) { float d = x[j] - mu; ss += d * d; }
#pragma unroll
  for (int o = 32; o; o >>= 1) ss += __shfl_xor(ss, o);
  if ((tid & 63) == 0) red[4 + (tid >> 6)] = ss;
  __syncthreads();
  float var = (red[4] + red[5] + red[6] + red[7]) * (1.f / 1024.f);
  float rstd = rsqrtf(var + 1e-5f);
  float4v vg = ((const float4v*)g)[tid];
  float4v vbe = ((const float4v*)be)[tid];
  float4v y;
#pragma unroll
  for (int j = 0; j < 4; ++j) y[j] = (x[j] - mu) * rstd * vg[j] + vbe[j];
  ((float4v*)(outf + r * 1024))[tid] = y;
  if (outb) {
    short4v ob;
#pragma unroll
    for (int j = 0; j < 4; ++j) ob[j] = f2bf(y[j]);
    ((short4v*)(outb + r * 1024))[tid] = ob;
  }
}

// ---------------- host launcher ----------------

extern "C" void kernel_launch(void* const* d_in, const int* in_sizes, int n_in,
                              void* d_out, int out_size, void* d_ws, size_t ws_size,
                              hipStream_t stream) {
  const float* X  = (const float*)d_in[0];
  const float* Wq = (const float*)d_in[1];
  const float* bq = (const float*)d_in[2];
  const float* Wk = (const float*)d_in[3];
  const float* bk = (const float*)d_in[4];
  const float* Wv = (const float*)d_in[5];
  const float* bv = (const float*)d_in[6];
  const float* W1 = (const float*)d_in[7];
  const float* b1 = (const float*)d_in[8];
  const float* W2 = (const float*)d_in[9];
  const float* b2 = (const float*)d_in[10];
  const float* W3 = (const float*)d_in[11];
  const float* b3 = (const float*)d_in[12];
  const float* g1  = (const float*)d_in[13];
  const float* be1 = (const float*)d_in[14];
  const float* g2  = (const float*)d_in[15];
  const float* be2 = (const float*)d_in[16];

  char* ws = (char*)d_ws;
  short* Xb     = (short*)(ws + 0);
  short* Wqkvt  = (short*)(ws + 16777216);
  short* W1t    = (short*)(ws + 23068672);
  short* W2t    = (short*)(ws + 25165824);
  short* W3t    = (short*)(ws + 27262976);
  float* bqkv   = (float*)(ws + 29360128);
  short* qkv    = (short*)(ws + 29372416);
  short* vT     = (short*)(ws + 79704064);
  short* scores = (short*)(ws + 96481280);
  float* ctx    = (float*)(ws + 29372416);
  float* h      = (float*)(ws + 96481280);
  short* hb     = (short*)(ws + 0);
  short* m1     = (short*)(ws + 29372416);
  short* m2     = (short*)(ws + 46149632);
  float* m3     = (float*)(ws + 62926848);
  float* out    = (float*)d_out;

  cast_x_k<<<8192, 256, 0, stream>>>(X, Xb);
  wcast_k<<<dim3(32, 32, 7), 256, 0, stream>>>(Wq, Wk, Wv, W1, W2, W3,
                                               bq, bk, bv,
                                               Wqkvt, W1t, W2t, W3t, bqkv);

  // QKV: [8192,1024] x [3072,1024]^T -> bf16 [8192,3072]
  gemm256<<<dim3(32, 12, 1), 512, 0, stream>>>(
      Xb, Wqkvt, bqkv, 1.0f, qkv, 1024, 1024, 1024, 3072, 0, 0, 0, 1);

  tv_k<<<dim3(32, 64, 4), 256, 0, stream>>>(qkv, vT);

  // scores[b] = q k^T / 32 -> bf16 [2048,2048]
  gemm256<<<dim3(8, 8, 4), 512, 0, stream>>>(
      qkv, qkv + 1024, nullptr, 0.03125f, scores, 1024, 3072, 3072, 2048,
      (long)2048 * 3072, (long)2048 * 3072, (long)2048 * 2048, 0);

  softmax_k<<<8192, 256, 0, stream>>>(scores);

  // ctx[b] = attn @ v (fp32 out)
  gemm128<<<dim3(8, 8, 4), 512, 0, stream>>>(
      scores, vT, nullptr, 1.0f, ctx, 2048, 2048, 2048, 1024,
      (long)2048 * 2048, (long)1024 * 2048, (long)2048 * 1024, 4);

  addln_k<<<8192, 256, 0, stream>>>(ctx, X, g1, be1, h, hb);

  gemm128<<<dim3(32, 8, 1), 512, 0, stream>>>(
      hb, W1t, b1, 1.0f, m1, 1024, 1024, 1024, 1024, 0, 0, 0, 3);
  gemm128<<<dim3(32, 8, 1), 512, 0, stream>>>(
      m1, W2t, b2, 1.0f, m2, 1024, 1024, 1024, 1024, 0, 0, 0, 3);
  gemm128<<<dim3(32, 8, 1), 512, 0, stream>>>(
      m2, W3t, b3, 1.0f, m3, 1024, 1024, 1024, 1024, 0, 0, 0, 5);

  addln_k<<<8192, 256, 0, stream>>>(m3, h, g2, be2, out, nullptr);
}

// Round 6
// 309.760 us; speedup vs baseline: 1.2746x; 1.0052x over previous
//
#include <hip/hip_runtime.h>
#include <hip/hip_bf16.h>

// TransformerBlock: N=4, T=2048, D=1024. bf16 MFMA 16x16x32, NT GEMMs.
// R6: single GEMM core "gemmTB": 256x128 tile, BK=32, triple-buffered LDS
// (72 KB -> 2 blocks/CU), stage issued 2 K-tiles ahead, counted vmcnt(3)
// mid-loop (never drains), ONE barrier per K-tile, XOR-swizzled LDS with
// immediate-offset ds_reads. Overlap comes from 2 resident blocks per CU
// (m97/m114 mechanism) instead of intra-block phase juggling.

typedef __attribute__((ext_vector_type(8))) short short8;
typedef __attribute__((ext_vector_type(4))) short short4v;
typedef __attribute__((ext_vector_type(4))) float float4v;

#define DEVI static __device__ __forceinline__

DEVI float bf2f(short s) {
  union { unsigned u; float f; } c;
  c.u = ((unsigned)(unsigned short)s) << 16;
  return c.f;
}
DEVI short f2bf(float f) {
  union { __hip_bfloat16 h; short s; } c;
  c.h = __float2bfloat16(f);
  return c.s;
}
DEVI void gload_lds16(const void* g, void* l) {
  __builtin_amdgcn_global_load_lds(
      (const __attribute__((address_space(1))) void*)g,
      (__attribute__((address_space(3))) void*)l, 16, 0, 0);
}

#define MFMA16 __builtin_amdgcn_mfma_f32_16x16x32_bf16
#define CFENCE asm volatile("" ::: "memory")
#define SCHEDB __builtin_amdgcn_sched_barrier(0)

// ---------------- 256x128 GEMM, BK=32, triple-buffer, 2 blocks/CU ----------------
// LDS buffer i (i=0,1,2) at byte i*24576: A tile 256x32 (16 KB) @ +0,
// B tile 128x32 (8 KB) @ +16384. Row = 64 B = 4 x 16B chunks; swizzle c ^= row&3.
// flags: 1=bias, 2=relu, 4=fp32 output (else bf16)
__global__ __launch_bounds__(512, 4) void gemmTB(
    const short* __restrict__ A, const short* __restrict__ B,
    const float* __restrict__ bias, float alpha, void* __restrict__ Cout,
    int K, int lda, int ldb, int ldc,
    long sA, long sB, long sC, int flags)
{
  __shared__ __attribute__((aligned(16))) short lds[36864];  // 72 KB

  const int tid  = threadIdx.x;
  const int lane = tid & 63;
  const int wid  = tid >> 6;
  const int wm = wid >> 1, wn = wid & 1;   // 4(M) x 2(N); wave owns 64x64
  const int lr = lane & 15;
  const int kq = lane >> 4;

  const long m0 = (long)blockIdx.x * 256;
  const long n0 = (long)blockIdx.y * 128;
  const short* Ab = A + (long)blockIdx.z * sA;
  const short* Bb = B + (long)blockIdx.z * sB;

  // ---- staging mapping (linear LDS dest; source column pre-swizzled) ----
  // A unit u (u=0,1): row = u*128 + (tid>>2), chunk = tid&3 -> dest = u*8192 + tid*16
  // B:               row = tid>>2,           chunk = tid&3 -> dest = 16384 + tid*16
  const int sc8 = (((tid & 3) ^ ((tid >> 2) & 3)) << 3);  // swizzled src col (elements)
  const short* pA0 = Ab + (m0 + (tid >> 2)) * (long)lda + sc8;         // rows 0..127
  const short* pA1 = Ab + (m0 + 128 + (tid >> 2)) * (long)lda + sc8;   // rows 128..255
  const short* pB  = Bb + (n0 + (tid >> 2)) * (long)ldb + sc8;

  char* ldsB = (char*)lds;
  const int dst0 = tid * 16;

  auto stage = [&](int bs, int kt) {
    const long ko = (long)kt * 32;
    gload_lds16(pA0 + ko, ldsB + bs + dst0);
    gload_lds16(pA1 + ko, ldsB + bs + 8192 + dst0);
    gload_lds16(pB  + ko, ldsB + bs + 16384 + dst0);
  };

  // ---- read addressing: one base per operand + immediate offsets ----
  // A frag fm: row = wm*64 + fm*16 + lr -> off = row*64 + ((kq^(lr&3))<<4)
  //          = [ (wm*64+lr)*64 + ((kq^(lr&3))<<4) ] + fm*1024
  const int swz = ((kq ^ (lr & 3)) << 4);
  const int baseA = (wm * 64 + lr) * 64 + swz;
  const int baseB = 16384 + (wn * 64 + lr) * 64 + swz;

  float4v acc[4][4];
#pragma unroll
  for (int m = 0; m < 4; ++m)
#pragma unroll
    for (int n = 0; n < 4; ++n)
#pragma unroll
      for (int i = 0; i < 4; ++i) acc[m][n][i] = 0.f;

  const int NT = K >> 5;

  // prologue: stage tiles 0,1; vmcnt(3) -> tile0 complete (tile1's 3 may fly)
  stage(0, 0);
  stage(24576, 1);
  asm volatile("s_waitcnt vmcnt(3)" ::: "memory");
  __builtin_amdgcn_s_barrier();
  CFENCE;

  int bsR = 0;          // buffer holding tile t
  int bsS = 2 * 24576;  // buffer for tile t+2

  for (int t = 0; t < NT; ++t) {
    // stage 2 ahead (skipped in the last two iterations)
    if (t + 2 < NT) stage(bsS, t + 2);

    // reads of tile t (8 x ds_read_b128, immediate offsets off one add each)
    const char* rA = ldsB + (bsR + baseA);
    const char* rB = ldsB + (bsR + baseB);
    short8 a0 = *(const short8*)(rA);
    short8 a1 = *(const short8*)(rA + 1024);
    short8 a2 = *(const short8*)(rA + 2048);
    short8 a3 = *(const short8*)(rA + 3072);
    short8 b0 = *(const short8*)(rB);
    short8 b1 = *(const short8*)(rB + 1024);
    short8 b2 = *(const short8*)(rB + 2048);
    short8 b3 = *(const short8*)(rB + 3072);

    asm volatile("s_waitcnt lgkmcnt(0)" ::: "memory");
    SCHEDB;
    __builtin_amdgcn_s_setprio(1);
    acc[0][0] = MFMA16(a0, b0, acc[0][0], 0, 0, 0);
    acc[0][1] = MFMA16(a0, b1, acc[0][1], 0, 0, 0);
    acc[0][2] = MFMA16(a0, b2, acc[0][2], 0, 0, 0);
    acc[0][3] = MFMA16(a0, b3, acc[0][3], 0, 0, 0);
    acc[1][0] = MFMA16(a1, b0, acc[1][0], 0, 0, 0);
    acc[1][1] = MFMA16(a1, b1, acc[1][1], 0, 0, 0);
    acc[1][2] = MFMA16(a1, b2, acc[1][2], 0, 0, 0);
    acc[1][3] = MFMA16(a1, b3, acc[1][3], 0, 0, 0);
    acc[2][0] = MFMA16(a2, b0, acc[2][0], 0, 0, 0);
    acc[2][1] = MFMA16(a2, b1, acc[2][1], 0, 0, 0);
    acc[2][2] = MFMA16(a2, b2, acc[2][2], 0, 0, 0);
    acc[2][3] = MFMA16(a2, b3, acc[2][3], 0, 0, 0);
    acc[3][0] = MFMA16(a3, b0, acc[3][0], 0, 0, 0);
    acc[3][1] = MFMA16(a3, b1, acc[3][1], 0, 0, 0);
    acc[3][2] = MFMA16(a3, b2, acc[3][2], 0, 0, 0);
    acc[3][3] = MFMA16(a3, b3, acc[3][3], 0, 0, 0);
    __builtin_amdgcn_s_setprio(0);

    // counted checkpoint: tile t+1 complete, tile t+2 stays in flight
    if (t + 2 < NT) { asm volatile("s_waitcnt vmcnt(3)" ::: "memory"); }
    else            { asm volatile("s_waitcnt vmcnt(0)" ::: "memory"); }
    __builtin_amdgcn_s_barrier();
    CFENCE;

    bsR = (bsR == 2 * 24576) ? 0 : bsR + 24576;
    bsS = (bsS == 2 * 24576) ? 0 : bsS + 24576;
  }

  // ---- epilogue ----
  const int dob = flags & 1, dor = flags & 2, f32o = flags & 4;
  float* Cf = (float*)Cout + (long)blockIdx.z * sC;
  short* Cb = (short*)Cout + (long)blockIdx.z * sC;
  const long r0 = m0 + wm * 64 + kq * 4;
  const long c0 = n0 + wn * 64 + lr;
#pragma unroll
  for (int m = 0; m < 4; ++m)
#pragma unroll
    for (int n = 0; n < 4; ++n) {
      const long c = c0 + n * 16;
      float bv = dob ? bias[c] : 0.f;
#pragma unroll
      for (int i = 0; i < 4; ++i) {
        const long r = r0 + m * 16 + i;
        float v = acc[m][n][i] * alpha + bv;
        if (dor) v = fmaxf(v, 0.f);
        if (f32o) Cf[r * ldc + c] = v;
        else      Cb[r * ldc + c] = f2bf(v);
      }
    }
}

// ---------------- elementwise / utility kernels ----------------

__global__ __launch_bounds__(256) void cast_x_k(const float* __restrict__ X,
                                                short* __restrict__ Xb) {
  int i = blockIdx.x * 256 + threadIdx.x;
  float4v v = ((const float4v*)X)[i];
  short4v o;
#pragma unroll
  for (int j = 0; j < 4; ++j) o[j] = f2bf(v[j]);
  ((short4v*)Xb)[i] = o;
}

// all 6 weight transposes + bias concat in one launch; grid (32,32,7)
__global__ __launch_bounds__(256) void wcast_k(
    const float* __restrict__ Wq, const float* __restrict__ Wk,
    const float* __restrict__ Wv, const float* __restrict__ W1,
    const float* __restrict__ W2, const float* __restrict__ W3,
    const float* __restrict__ bq, const float* __restrict__ bk,
    const float* __restrict__ bv,
    short* __restrict__ Wqkvt, short* __restrict__ W1t,
    short* __restrict__ W2t, short* __restrict__ W3t,
    float* __restrict__ bqkv) {
  const int z = blockIdx.z;
  if (z == 6) {
    if (blockIdx.y != 0 || blockIdx.x >= 12) return;
    int i = blockIdx.x * 256 + threadIdx.x;
    bqkv[i] = i < 1024 ? bq[i] : (i < 2048 ? bk[i - 1024] : bv[i - 2048]);
    return;
  }
  const float* W = z == 0 ? Wq : z == 1 ? Wk : z == 2 ? Wv : z == 3 ? W1 : z == 4 ? W2 : W3;
  short* Wt = z == 0 ? Wqkvt : z == 1 ? Wqkvt + 1048576 : z == 2 ? Wqkvt + 2097152
            : z == 3 ? W1t : z == 4 ? W2t : W3t;
  __shared__ float tile[32][33];
  int tx = threadIdx.x & 31, ty = threadIdx.x >> 5;
  int c0 = blockIdx.x * 32, r0 = blockIdx.y * 32;
#pragma unroll
  for (int r = ty; r < 32; r += 8)
    tile[r][tx] = W[(long)(r0 + r) * 1024 + c0 + tx];
  __syncthreads();
#pragma unroll
  for (int r = ty; r < 32; r += 8)
    Wt[(long)(c0 + r) * 1024 + r0 + tx] = f2bf(tile[tx][r]);
}

__global__ __launch_bounds__(256) void tv_k(const short* __restrict__ qkv,
                                            short* __restrict__ vT) {
  __shared__ short tile[32][33];
  int b = blockIdx.z;
  int tx = threadIdx.x & 31, ty = threadIdx.x >> 5;
  int d0 = blockIdx.x * 32, t0 = blockIdx.y * 32;
#pragma unroll
  for (int r = ty; r < 32; r += 8)
    tile[r][tx] = qkv[((long)(b * 2048 + t0 + r)) * 3072 + 2048 + d0 + tx];
  __syncthreads();
#pragma unroll
  for (int r = ty; r < 32; r += 8)
    vT[(long)b * 2097152 + (long)(d0 + r) * 2048 + t0 + tx] = tile[tx][r];
}

__global__ __launch_bounds__(256) void softmax_k(short* __restrict__ s) {
  __shared__ float red[8];
  long r = blockIdx.x;
  short* p = s + r * 2048;
  int tid = threadIdx.x;
  short8 raw = *(short8*)&p[tid * 8];
  float v[8];
  float mx = -1e30f;
#pragma unroll
  for (int j = 0; j < 8; ++j) { v[j] = bf2f(raw[j]); mx = fmaxf(mx, v[j]); }
#pragma unroll
  for (int o = 32; o; o >>= 1) mx = fmaxf(mx, __shfl_xor(mx, o));
  if ((tid & 63) == 0) red[tid >> 6] = mx;
  __syncthreads();
  mx = fmaxf(fmaxf(red[0], red[1]), fmaxf(red[2], red[3]));
  float sum = 0.f;
#pragma unroll
  for (int j = 0; j < 8; ++j) { v[j] = __expf(v[j] - mx); sum += v[j]; }
#pragma unroll
  for (int o = 32; o; o >>= 1) sum += __shfl_xor(sum, o);
  if ((tid & 63) == 0) red[4 + (tid >> 6)] = sum;
  __syncthreads();
  float inv = 1.f / (red[4] + red[5] + red[6] + red[7]);
  short8 o8;
#pragma unroll
  for (int j = 0; j < 8; ++j) o8[j] = f2bf(v[j] * inv);
  *(short8*)&p[tid * 8] = o8;
}

__global__ __launch_bounds__(256) void addln_k(const float* __restrict__ a,
                                               const float* __restrict__ b,
                                               const float* __restrict__ g,
                                               const float* __restrict__ be,
                                               float* __restrict__ outf,
                                               short* __restrict__ outb) {
  __shared__ float red[8];
  long r = blockIdx.x;
  int tid = threadIdx.x;
  float4v va = ((const float4v*)(a + r * 1024))[tid];
  float4v vb = ((const float4v*)(b + r * 1024))[tid];
  float x[4]; float s = 0.f;
#pragma unroll
  for (int j = 0; j < 4; ++j) { x[j] = va[j] + vb[j]; s += x[j]; }
#pragma unroll
  for (int o = 32; o; o >>= 1) s += __shfl_xor(s, o);
  if ((tid & 63) == 0) red[tid >> 6] = s;
  __syncthreads();
  float mu = (red[0] + red[1] + red[2] + red[3]) * (1.f / 1024.f);
  float ss = 0.f;
#pragma unroll
  for (int j = 0; j < 4; ++j) { float d = x[j] - mu; ss += d * d; }
#pragma unroll
  for (int o = 32; o; o >>= 1) ss += __shfl_xor(ss, o);
  if ((tid & 63) == 0) red[4 + (tid >> 6)] = ss;
  __syncthreads();
  float var = (red[4] + red[5] + red[6] + red[7]) * (1.f / 1024.f);
  float rstd = rsqrtf(var + 1e-5f);
  float4v vg = ((const float4v*)g)[tid];
  float4v vbe = ((const float4v*)be)[tid];
  float4v y;
#pragma unroll
  for (int j = 0; j < 4; ++j) y[j] = (x[j] - mu) * rstd * vg[j] + vbe[j];
  ((float4v*)(outf + r * 1024))[tid] = y;
  if (outb) {
    short4v ob;
#pragma unroll
    for (int j = 0; j < 4; ++j) ob[j] = f2bf(y[j]);
    ((short4v*)(outb + r * 1024))[tid] = ob;
  }
}

// ---------------- host launcher ----------------

extern "C" void kernel_launch(void* const* d_in, const int* in_sizes, int n_in,
                              void* d_out, int out_size, void* d_ws, size_t ws_size,
                              hipStream_t stream) {
  const float* X  = (const float*)d_in[0];
  const float* Wq = (const float*)d_in[1];
  const float* bq = (const float*)d_in[2];
  const float* Wk = (const float*)d_in[3];
  const float* bk = (const float*)d_in[4];
  const float* Wv = (const float*)d_in[5];
  const float* bv = (const float*)d_in[6];
  const float* W1 = (const float*)d_in[7];
  const float* b1 = (const float*)d_in[8];
  const float* W2 = (const float*)d_in[9];
  const float* b2 = (const float*)d_in[10];
  const float* W3 = (const float*)d_in[11];
  const float* b3 = (const float*)d_in[12];
  const float* g1  = (const float*)d_in[13];
  const float* be1 = (const float*)d_in[14];
  const float* g2  = (const float*)d_in[15];
  const float* be2 = (const float*)d_in[16];

  char* ws = (char*)d_ws;
  short* Xb     = (short*)(ws + 0);
  short* Wqkvt  = (short*)(ws + 16777216);
  short* W1t    = (short*)(ws + 23068672);
  short* W2t    = (short*)(ws + 25165824);
  short* W3t    = (short*)(ws + 27262976);
  float* bqkv   = (float*)(ws + 29360128);
  short* qkv    = (short*)(ws + 29372416);
  short* vT     = (short*)(ws + 79704064);
  short* scores = (short*)(ws + 96481280);
  float* ctx    = (float*)(ws + 29372416);
  float* h      = (float*)(ws + 96481280);
  short* hb     = (short*)(ws + 0);
  short* m1     = (short*)(ws + 29372416);
  short* m2     = (short*)(ws + 46149632);
  float* m3     = (float*)(ws + 62926848);
  float* out    = (float*)d_out;

  cast_x_k<<<8192, 256, 0, stream>>>(X, Xb);
  wcast_k<<<dim3(32, 32, 7), 256, 0, stream>>>(Wq, Wk, Wv, W1, W2, W3,
                                               bq, bk, bv,
                                               Wqkvt, W1t, W2t, W3t, bqkv);

  // QKV: [8192,1024] x [3072,1024]^T -> bf16 [8192,3072]; grid 32x24=768
  gemmTB<<<dim3(32, 24, 1), 512, 0, stream>>>(
      Xb, Wqkvt, bqkv, 1.0f, qkv, 1024, 1024, 1024, 3072, 0, 0, 0, 1);

  tv_k<<<dim3(32, 64, 4), 256, 0, stream>>>(qkv, vT);

  // scores[b] = q k^T / 32 -> bf16 [2048,2048]; grid 8x16x4=512 (all co-resident)
  gemmTB<<<dim3(8, 16, 4), 512, 0, stream>>>(
      qkv, qkv + 1024, nullptr, 0.03125f, scores, 1024, 3072, 3072, 2048,
      (long)2048 * 3072, (long)2048 * 3072, (long)2048 * 2048, 0);

  softmax_k<<<8192, 256, 0, stream>>>(scores);

  // ctx[b] = attn @ v (fp32 out); grid 8x8x4=256
  gemmTB<<<dim3(8, 8, 4), 512, 0, stream>>>(
      scores, vT, nullptr, 1.0f, ctx, 2048, 2048, 2048, 1024,
      (long)2048 * 2048, (long)1024 * 2048, (long)2048 * 1024, 4);

  addln_k<<<8192, 256, 0, stream>>>(ctx, X, g1, be1, h, hb);

  // MLP: grid 32x8=256 each
  gemmTB<<<dim3(32, 8, 1), 512, 0, stream>>>(
      hb, W1t, b1, 1.0f, m1, 1024, 1024, 1024, 1024, 0, 0, 0, 3);
  gemmTB<<<dim3(32, 8, 1), 512, 0, stream>>>(
      m1, W2t, b2, 1.0f, m2, 1024, 1024, 1024, 1024, 0, 0, 0, 3);
  gemmTB<<<dim3(32, 8, 1), 512, 0, stream>>>(
      m2, W3t, b3, 1.0f, m3, 1024, 1024, 1024, 1024, 0, 0, 0, 5);

  addln_k<<<8192, 256, 0, stream>>>(m3, h, g2, be2, out, nullptr);
}